// Round 4
// baseline (845.327 us; speedup 1.0000x reference)
//
#include <hip/hip_runtime.h>

typedef unsigned short u16;
typedef unsigned short u16x8 __attribute__((ext_vector_type(8)));
typedef __bf16 bf16x8 __attribute__((ext_vector_type(8)));
typedef float f32x4 __attribute__((ext_vector_type(4)));
typedef float f32x16 __attribute__((ext_vector_type(16)));

#define N_NODES 100000
#define N_EDGES 1600000
#define TM 64      // mlp rows per block
#define HP1 1032   // h1 LDS row stride (1024 + 8 pad) in bf16 (16B-aligned rows)
#define SCP2 36    // phase-C scratch row stride (32 + 4 pad) in bf16
#define WTP 65     // sage LDS weight row stride: 65 -> bank = c%32 (2-way, free) and 39.4 KB/block -> 4 blocks/CU

__device__ __forceinline__ u16 f2bf(float f) {
    unsigned int u = __float_as_uint(f);
    u = (u + 0x7FFFu + ((u >> 16) & 1u)) >> 16;   // RNE
    return (u16)u;
}

// ---------------- transpose + f32->bf16 convert: out[c][r] = in[r][c] ----------------
__global__ __launch_bounds__(256) void transpose_cvt(const float* __restrict__ in,
                                                     u16* __restrict__ out, int R, int C) {
    __shared__ float tile[32][33];
    int tx = threadIdx.x, ty = threadIdx.y;
    int cb = blockIdx.x * 32, rb = blockIdx.y * 32;
#pragma unroll
    for (int i = 0; i < 4; ++i) {
        int r = rb + ty + i * 8, c = cb + tx;
        tile[ty + i * 8][tx] = (r < R && c < C) ? in[(size_t)r * C + c] : 0.f;
    }
    __syncthreads();
#pragma unroll
    for (int i = 0; i < 4; ++i) {
        int c = cb + ty + i * 8, r = rb + tx;
        if (r < R && c < C) out[(size_t)c * R + r] = f2bf(tile[tx][ty + i * 8]);
    }
}

// ---------------- pack Wm2 [k=1024][n=1024] f32 -> per-(wave8,t,j,lane) MFMA-fragment order, bf16 ----------------
// v5 layout: 8 streams (waves) x 128 cols; chunk = w*256 + t*4 + j, j=0..3
__global__ __launch_bounds__(256) void pack_w2(const float* __restrict__ Wm2,
                                               u16* __restrict__ W2P) {
    int idx = blockIdx.x * 256 + threadIdx.x;   // 0 .. 131071
    int lane = idx & 63;
    int chunk = idx >> 6;           // w*256 + t*4 + j
    int j = chunk & 3;
    int t = (chunk >> 2) & 63;
    int w = chunk >> 8;             // 0..7
    int n = w * 128 + j * 32 + (lane & 31);
    int kbase = t * 16 + (lane >> 5) * 8;
    u16x8 tmp;
#pragma unroll
    for (int i = 0; i < 8; ++i) tmp[i] = f2bf(Wm2[(size_t)(kbase + i) * 1024 + n]);
    *(u16x8*)(W2P + (size_t)idx * 8) = tmp;
}

// ---------------- CSR build: histogram, multi-block scan, fill ----------------
__global__ __launch_bounds__(256) void hist_deg(const int* __restrict__ dst,
                                                int* __restrict__ deg, int E) {
    int i = blockIdx.x * 256 + threadIdx.x;
    int st = gridDim.x * 256;
    for (; i < E; i += st) atomicAdd(&deg[dst[i]], 1);
}

// per-block exclusive scan (1024 elems/block) + block totals
__global__ __launch_bounds__(1024) void scan_blk(const int* __restrict__ deg,
                                                 int* __restrict__ offs,
                                                 int* __restrict__ bsum, int N) {
    __shared__ int wsum[17];
    const int tid = threadIdx.x;
    const int lane = tid & 63;
    const int w = tid >> 6;
    const int idx = blockIdx.x * 1024 + tid;
    int v = (idx < N) ? deg[idx] : 0;
    int x = v;
#pragma unroll
    for (int d = 1; d < 64; d <<= 1) {
        int t = __shfl_up(x, d);
        if (lane >= d) x += t;
    }
    if (lane == 63) wsum[w + 1] = x;
    __syncthreads();
    if (tid == 0) {
        wsum[0] = 0;
        int s = 0;
#pragma unroll
        for (int i = 1; i <= 16; ++i) { s += wsum[i]; wsum[i] = s; }
        bsum[blockIdx.x] = s;
    }
    __syncthreads();
    if (idx < N) offs[idx] = wsum[w] + x - v;
}

// single-wave exclusive scan of block totals (nb <= a few hundred)
__global__ __launch_bounds__(64) void scan_top(int* __restrict__ bsum, int nb) {
    const int lane = threadIdx.x;
    int run = 0;
    for (int base = 0; base < nb; base += 64) {
        int idx = base + lane;
        int v = (idx < nb) ? bsum[idx] : 0;
        int x = v;
#pragma unroll
        for (int d = 1; d < 64; d <<= 1) {
            int t = __shfl_up(x, d);
            if (lane >= d) x += t;
        }
        if (idx < nb) bsum[idx] = run + x - v;
        run += __shfl(x, 63);
    }
}

__global__ __launch_bounds__(1024) void scan_add(int* __restrict__ offs,
                                                 const int* __restrict__ bsum, int N) {
    int idx = blockIdx.x * 1024 + threadIdx.x;
    if (idx < N) offs[idx] += bsum[blockIdx.x];
}

// fill: mutates offs[n] exclusive-start -> inclusive-end; eidx gets src ids
__global__ __launch_bounds__(256) void fill_csr(const int* __restrict__ src,
                                                const int* __restrict__ dst,
                                                int* __restrict__ offs,
                                                int* __restrict__ eidx, int E) {
    int i = blockIdx.x * 256 + threadIdx.x;
    int st = gridDim.x * 256;
    for (; i < E; i += st) {
        int pos = atomicAdd(&offs[dst[i]], 1);
        eidx[pos] = src[i];
    }
}

// ---------------- fused agg + SAGE: gather-mean (quarter-wave) -> per-wave LDS -> gemm.
// out = mean @ Wl + bl + xin @ Wr.  v5: offs/deg prefetched one group ahead (removes the
// dependent-load step at each group start); WTP=65 (bank-friendly, 4 blocks/CU).
template <int CO>
__global__ __launch_bounds__(256) void agg_sage(const f32x4* __restrict__ x4,
                                                const int* __restrict__ offs,
                                                const int* __restrict__ deg,
                                                const int* __restrict__ eidx,
                                                const float* __restrict__ Wl,
                                                const float* __restrict__ Wr,
                                                const float* __restrict__ bl,
                                                float* __restrict__ out,
                                                float* __restrict__ ssum,
                                                float* __restrict__ ssq, int N) {
    __shared__ float WlT[CO * WTP], WrT[CO * WTP];   // [c][k], stride 65
    __shared__ float rsum[4 * CO], rsq[4 * CO];
    __shared__ __align__(16) f32x4 meanLds[4][4][16]; // [wave][node][k4] = 4 KB
    for (int i = threadIdx.x; i < 64 * CO; i += 256) {
        int k = i / CO, c2 = i % CO;
        WlT[c2 * WTP + k] = Wl[i];
        WrT[c2 * WTP + k] = Wr[i];
    }
    __syncthreads();
    const int lane = threadIdx.x & 63;
    const int wv = threadIdx.x >> 6;
    const int q = lane >> 4, l16 = lane & 15;
    const int c = lane % CO;
    const int sub = lane / CO;
    const int wid = (blockIdx.x * 256 + threadIdx.x) >> 6;
    const int nw = (gridDim.x * 256) >> 6;
    const float bias = bl[c];
    const f32x4* wlrow = (const f32x4*)(WlT + c * WTP);
    const f32x4* wrrow = (const f32x4*)(WrT + c * WTP);
    constexpr int NB = (CO == 64) ? 4 : 2;
    const int bbase = (CO == 64) ? 0 : sub * 2;
    float lsum = 0.f, lsq = 0.f;
    // prefetch first group's offs/deg
    int pn = wid * 4 + q;
    int pend = (pn < N) ? offs[pn] : 0;
    int pd   = (pn < N) ? deg[pn] : 0;
    for (int n0 = wid * 4; n0 < N; n0 += nw * 4) {
        const int end = pend;      // inclusive end after fill_csr
        const int d = pd;
        {   // issue next group's offs/deg now; consumed next iteration
            int nn = n0 + nw * 4 + q;
            if (nn < N) { pend = offs[nn]; pd = deg[nn]; }
        }
        // ---- gather phase: quarter-wave per node
        {
            int i = end - d;
            f32x4 s = {0.f, 0.f, 0.f, 0.f};
            for (; i + 8 <= end; i += 8) {
                int e0 = eidx[i],     e1 = eidx[i + 1], e2 = eidx[i + 2], e3 = eidx[i + 3];
                int e4 = eidx[i + 4], e5 = eidx[i + 5], e6 = eidx[i + 6], e7 = eidx[i + 7];
                f32x4 v0 = x4[e0 * 16 + l16];
                f32x4 v1 = x4[e1 * 16 + l16];
                f32x4 v2 = x4[e2 * 16 + l16];
                f32x4 v3 = x4[e3 * 16 + l16];
                f32x4 v4 = x4[e4 * 16 + l16];
                f32x4 v5 = x4[e5 * 16 + l16];
                f32x4 v6 = x4[e6 * 16 + l16];
                f32x4 v7 = x4[e7 * 16 + l16];
                s = s + ((v0 + v1) + (v2 + v3)) + ((v4 + v5) + (v6 + v7));
            }
            for (; i + 2 <= end; i += 2) {
                int e0 = eidx[i], e1 = eidx[i + 1];
                s = s + x4[e0 * 16 + l16] + x4[e1 * 16 + l16];
            }
            if (i < end) s = s + x4[eidx[i] * 16 + l16];
            float inv = 1.0f / fmaxf((float)d, 1.0f);
            f32x4 r = {s.x * inv, s.y * inv, s.z * inv, s.w * inv};
            meanLds[wv][q][l16] = r;
        }
        // ---- gemm phase (pa from LDS broadcast)
        float am[NB], ax[NB];
#pragma unroll
        for (int b = 0; b < NB; ++b) { am[b] = 0.f; ax[b] = 0.f; }
#pragma unroll 4
        for (int k4 = 0; k4 < 16; ++k4) {
            f32x4 wl = wlrow[k4];
            f32x4 wr = wrrow[k4];
#pragma unroll
            for (int b = 0; b < NB; ++b) {
                f32x4 pa = meanLds[wv][bbase + b][k4];
                f32x4 px = x4[(size_t)(n0 + bbase + b) * 16 + k4];
                am[b] += pa.x * wl.x + pa.y * wl.y + pa.z * wl.z + pa.w * wl.w;
                ax[b] += px.x * wr.x + px.y * wr.y + px.z * wr.z + px.w * wr.w;
            }
        }
#pragma unroll
        for (int b = 0; b < NB; ++b) {
            float v = am[b] + ax[b] + bias;
            out[(size_t)(n0 + bbase + b) * CO + c] = v;
            lsum += v; lsq += v * v;
        }
    }
    if (CO == 32) {
        lsum += __shfl_xor(lsum, 32);
        lsq  += __shfl_xor(lsq, 32);
    }
    if (sub == 0) { rsum[wv * CO + c] = lsum; rsq[wv * CO + c] = lsq; }
    __syncthreads();
    if (threadIdx.x < CO) {
        float s = rsum[threadIdx.x] + rsum[CO + threadIdx.x] +
                  rsum[2 * CO + threadIdx.x] + rsum[3 * CO + threadIdx.x];
        float q2 = rsq[threadIdx.x] + rsq[CO + threadIdx.x] +
                   rsq[2 * CO + threadIdx.x] + rsq[3 * CO + threadIdx.x];
        atomicAdd(&ssum[threadIdx.x], s);
        atomicAdd(&ssq[threadIdx.x], q2);
    }
}

// ---------------- BN (batch stats) + ReLU, in place; optional bf16 copy ----------------
template <int CO, int WRITE_BF>
__global__ __launch_bounds__(256) void bn_relu(float* __restrict__ data,
                                               const float* __restrict__ ssum,
                                               const float* __restrict__ ssq,
                                               const float* __restrict__ g,
                                               const float* __restrict__ be,
                                               u16* __restrict__ xb, int N) {
    const float invN = 1.0f / (float)N_NODES;
    int idx = blockIdx.x * 256 + threadIdx.x;
    int total = N * CO;
    int stride = gridDim.x * 256;
    for (; idx < total; idx += stride) {
        int c = idx & (CO - 1);
        float mu = ssum[c] * invN;
        float var = ssq[c] * invN - mu * mu;
        float sc = rsqrtf(var + 1e-5f) * g[c];
        float v = (data[idx] - mu) * sc + be[c];
        v = fmaxf(v, 0.f);
        data[idx] = v;
        if (WRITE_BF) xb[idx] = f2bf(v);
    }
}

// ---------------- fused MLP v5: TM=64, 8 waves (512 thr), wave owns 128 cols.
// Halves the Phase-B LDS A-re-read (2 MB -> 1 MB per block) and ds-port pressure;
// doubles per-wave MFMA ILP (8 MFMA/t). __launch_bounds__(512,2) -> 256-VGPR budget,
// acc[2][4]=128 + bp[3][4]=48 + misc fits without spill (single-pass skeleton kept).
__global__ __launch_bounds__(512, 2) void mlp_fused(const u16* __restrict__ xt2b,   // [100032][32]
                                                    const u16* __restrict__ W1T,    // [1024][32]
                                                    const float* __restrict__ bm1,
                                                    const u16* __restrict__ W2P,    // packed, 2 MB
                                                    const float* __restrict__ bm2,
                                                    const u16* __restrict__ W3T,    // [16][1024]
                                                    const float* __restrict__ bm3,
                                                    float* __restrict__ probs,
                                                    float* __restrict__ logitsO) {
    __shared__ __align__(16) u16 h1s[TM * HP1];        // 132096 B (reused as f32 reduce buf)
    __shared__ __align__(16) u16 scr[8 * 16 * SCP2];   // 9216 B per-wave phase-C scratch
    const int tid = threadIdx.x;
    const int w = tid >> 6;          // 0..7
    const int lane = tid & 63;
    const int l16 = lane & 15;
    const int q = lane >> 4;
    const int m32 = lane & 31;       // 32x32 row/col index
    const int h8 = (lane >> 5) * 8;  // 32x32 k-offset
    const int row0 = blockIdx.x * TM;
    const int nb0 = w * 128;

    // per-wave packed-B stream base: frag (t,j) at wq + (t*4+j)*512
    const u16* wq = W2P + (size_t)w * 256 * 512 + (size_t)lane * 8;

    // ---- B pipeline preload (t=0,1,2) — issued before Phase A to hide latency
    bf16x8 bp[3][4];
#pragma unroll
    for (int s = 0; s < 3; ++s)
#pragma unroll
        for (int j = 0; j < 4; ++j)
            bp[s][j] = *(const bf16x8*)(wq + (s * 4 + j) * 512);

    // ---- Phase A: h1 rows [row0,row0+64) = relu(xt2 @ Wm1 + bm1) -> LDS (wave fills its 128 cols)
    {
        bf16x8 bW[8];
        float biasA[8];
#pragma unroll
        for (int nt = 0; nt < 8; ++nt) {
            const int n = nb0 + nt * 16 + l16;
            bW[nt] = *(const bf16x8*)(W1T + n * 32 + q * 8);
            biasA[nt] = bm1[n];
        }
#pragma unroll
        for (int mt = 0; mt < 4; ++mt) {
            const int grow = row0 + mt * 16 + l16;               // < 100032 (1563*64)
            bf16x8 a = *(const bf16x8*)(xt2b + grow * 32 + q * 8);
#pragma unroll
            for (int nt = 0; nt < 8; ++nt) {
                const int n = nb0 + nt * 16 + l16;
                f32x4 c = {0.f, 0.f, 0.f, 0.f};
                c = __builtin_amdgcn_mfma_f32_16x16x32_bf16(a, bW[nt], c, 0, 0, 0);
#pragma unroll
                for (int r = 0; r < 4; ++r)
                    h1s[(mt * 16 + q * 4 + r) * HP1 + n] = f2bf(fmaxf(c[r] + biasA[nt], 0.f));
            }
        }
    }
    __syncthreads();

    // ---- Phase B: 64 k-steps of 16; wave computes 2x4 32x32 tiles; fully unrolled, depth-3 B pipe
    f32x16 acc[2][4];
#pragma unroll
    for (int i2 = 0; i2 < 2; ++i2)
#pragma unroll
        for (int j = 0; j < 4; ++j)
#pragma unroll
            for (int r = 0; r < 16; ++r) acc[i2][j][r] = 0.f;

#pragma unroll
    for (int t = 0; t < 64; ++t) {
        const int s = t % 3;
        const int k0 = t * 16;
        bf16x8 a0 = *(const bf16x8*)(h1s + (0 * 32 + m32) * HP1 + k0 + h8);
        bf16x8 a1 = *(const bf16x8*)(h1s + (1 * 32 + m32) * HP1 + k0 + h8);
        __builtin_amdgcn_s_setprio(1);
#pragma unroll
        for (int j = 0; j < 4; ++j) {
            acc[0][j] = __builtin_amdgcn_mfma_f32_32x32x16_bf16(a0, bp[s][j], acc[0][j], 0, 0, 0);
            acc[1][j] = __builtin_amdgcn_mfma_f32_32x32x16_bf16(a1, bp[s][j], acc[1][j], 0, 0, 0);
        }
        __builtin_amdgcn_s_setprio(0);
        if (t + 3 < 64) {
#pragma unroll
            for (int j = 0; j < 4; ++j)
                bp[s][j] = *(const bf16x8*)(wq + ((t + 3) * 4 + j) * 512);
        }
    }

    // ---- epilogue + Phase C: per 16x32 chunk -> scratch (A-layout) -> logits MFMA
    float bias2[4];
    bf16x8 b3f[4];
#pragma unroll
    for (int j = 0; j < 4; ++j) {
        bias2[j] = bm2[nb0 + j * 32 + m32];
        b3f[j] = *(const bf16x8*)(W3T + l16 * 1024 + nb0 + j * 32 + q * 8);
    }
    f32x4 plog[4];
#pragma unroll
    for (int mt = 0; mt < 4; ++mt) plog[mt] = (f32x4){0.f, 0.f, 0.f, 0.f};
    u16* sw = scr + w * 16 * SCP2;

#pragma unroll
    for (int i2 = 0; i2 < 2; ++i2)
#pragma unroll
        for (int rh = 0; rh < 2; ++rh) {
            const int mt = i2 * 2 + rh;
#pragma unroll
            for (int j = 0; j < 4; ++j) {
#pragma unroll
                for (int rr = 0; rr < 8; ++rr) {
                    // 32x32 C-layout: row=(reg&3)+8*(reg>>2)+4*(lane>>5), col=lane&31
                    const int row16 = (rr & 3) + 8 * (rr >> 2) + 4 * (lane >> 5);
                    float v = acc[i2][j][rh * 8 + rr] + bias2[j];
                    sw[row16 * SCP2 + m32] = f2bf(fmaxf(v, 0.f));
                }
                bf16x8 a2 = *(const bf16x8*)(sw + l16 * SCP2 + q * 8);
                plog[mt] = __builtin_amdgcn_mfma_f32_16x16x32_bf16(a2, b3f[j], plog[mt], 0, 0, 0);
            }
        }

    // ---- cross-wave logit reduction (reuse h1s as f32 buffer: 8*4*64*16B = 32 KB)
    __syncthreads();
    f32x4* red = (f32x4*)h1s;
#pragma unroll
    for (int mt = 0; mt < 4; ++mt) red[(w * 4 + mt) * 64 + lane] = plog[mt];
    __syncthreads();

    if (w < 4) {                                   // wave w finalizes m-tile w
        f32x4 tot = red[w * 64 + lane];
#pragma unroll
        for (int w2 = 1; w2 < 8; ++w2) tot = tot + red[(w2 * 4 + w) * 64 + lane];
        const float b3v = bm3[l16];
#pragma unroll
        for (int r = 0; r < 4; ++r) {
            float v = tot[r] + b3v;
            float m = v;
            m = fmaxf(m, __shfl_xor(m, 1));
            m = fmaxf(m, __shfl_xor(m, 2));
            m = fmaxf(m, __shfl_xor(m, 4));
            m = fmaxf(m, __shfl_xor(m, 8));
            float e = __expf(v - m);
            float s = e;
            s += __shfl_xor(s, 1);
            s += __shfl_xor(s, 2);
            s += __shfl_xor(s, 4);
            s += __shfl_xor(s, 8);
            const int R = row0 + w * 16 + q * 4 + r;
            if (R < N_NODES) {
                logitsO[R * 16 + l16] = v;
                probs[R * 16 + l16] = e / s;
            }
        }
    }
}

extern "C" void kernel_launch(void* const* d_in, const int* in_sizes, int n_in,
                              void* d_out, int out_size, void* d_ws, size_t ws_size,
                              hipStream_t stream) {
    const float* x   = (const float*)d_in[0];
    const int*   ei  = (const int*)d_in[1];
    const int*   src = ei;
    const int*   dst = ei + N_EDGES;
    const float* W1l = (const float*)d_in[2];
    const float* b1l = (const float*)d_in[3];
    const float* W1r = (const float*)d_in[4];
    const float* g1  = (const float*)d_in[5];
    const float* be1 = (const float*)d_in[6];
    const float* W2l = (const float*)d_in[7];
    const float* b2l = (const float*)d_in[8];
    const float* W2r = (const float*)d_in[9];
    const float* g2  = (const float*)d_in[10];
    const float* be2 = (const float*)d_in[11];
    const float* Wm1 = (const float*)d_in[12];
    const float* bm1 = (const float*)d_in[13];
    const float* Wm2 = (const float*)d_in[14];
    const float* bm2 = (const float*)d_in[15];
    const float* Wm3 = (const float*)d_in[16];
    const float* bm3 = (const float*)d_in[17];

    float* probs  = (float*)d_out;                 // [N,16]
    float* logits = probs + 1600000;               // [N,16]
    float* xt1    = probs + 3200000;               // [N,64]
    float* xt2    = probs + 9600000;               // [N,32]

    char* wsb    = (char*)d_ws;
    int*  deg    = (int*)(wsb);                    //   400,000 B
    float* stats = (float*)(wsb + 400000);         //       768 B
    int*  offs   = (int*)(wsb + 400768);           //   400,000 B
    int*  eidx   = (int*)(wsb + 800768);           // 6,400,000 B
    int*  bsum   = (int*)(wsb + 7200768);          // scan block totals (dead after scan_add)
    u16*  xt2b   = (u16*)(wsb + 32800768);         // 6,402,048 B ([100032][32])
    u16*  W1T    = (u16*)(wsb + 39202816);         //    65,536 B
    u16*  W2P    = (u16*)(wsb + 39268352);         // 2,097,152 B (fragment-packed Wm2)
    u16*  W3T    = (u16*)(wsb + 41365504);         //    32,768 B  (end: 41,398,272)
    float* sum1 = stats, *sq1 = stats + 64, *sum2 = stats + 128, *sq2 = stats + 160;

    // zero deg + stats; zero xt2b tail rows 100000..100031
    hipMemsetAsync(wsb, 0, 400768, stream);
    hipMemsetAsync(xt2b + 100000 * 32, 0, 32 * 32 * sizeof(u16), stream);

    // weight transforms (bf16)
    transpose_cvt<<<dim3(32, 1),  dim3(32, 8), 0, stream>>>(Wm1, W1T, 32, 1024);
    pack_w2<<<512, 256, 0, stream>>>(Wm2, W2P);
    transpose_cvt<<<dim3(1, 32),  dim3(32, 8), 0, stream>>>(Wm3, W3T, 1024, 16);

    // ---- CSR build (once; reused by both layers)
    hist_deg<<<6250, 256, 0, stream>>>(dst, deg, N_EDGES);
    scan_blk<<<98, 1024, 0, stream>>>(deg, offs, bsum, N_NODES);
    scan_top<<<1, 64, 0, stream>>>(bsum, 98);
    scan_add<<<98, 1024, 0, stream>>>(offs, bsum, N_NODES);
    fill_csr<<<6250, 256, 0, stream>>>(src, dst, offs, eidx, N_EDGES);

    // ---- layer 1: fused gather-mean + SAGE gemm
    agg_sage<64><<<1024, 256, 0, stream>>>((const f32x4*)x, offs, deg, eidx,
                                           W1l, W1r, b1l, xt1, sum1, sq1, N_NODES);
    bn_relu<64, 0><<<4096, 256, 0, stream>>>(xt1, sum1, sq1, g1, be1, nullptr, N_NODES);

    // ---- layer 2: fused gather-mean + SAGE gemm
    agg_sage<32><<<1024, 256, 0, stream>>>((const f32x4*)xt1, offs, deg, eidx,
                                           W2l, W2r, b2l, xt2, sum2, sq2, N_NODES);
    bn_relu<32, 1><<<2048, 256, 0, stream>>>(xt2, sum2, sq2, g2, be2, xt2b, N_NODES);

    // ---- fused MLP + softmax: 512 threads, 8 waves x 128 cols
    mlp_fused<<<1563, 512, 0, stream>>>(xt2b, W1T, bm1, W2P, bm2, W3T, bm3, probs, logits);
}

// Round 6
// 781.646 us; speedup vs baseline: 1.0815x; 1.0815x over previous
//
#include <hip/hip_runtime.h>

typedef unsigned short u16;
typedef unsigned short u16x8 __attribute__((ext_vector_type(8)));
typedef __bf16 bf16x8 __attribute__((ext_vector_type(8)));
typedef float f32x4 __attribute__((ext_vector_type(4)));
typedef float f32x16 __attribute__((ext_vector_type(16)));

#define N_NODES 100000
#define N_EDGES 1600000
#define TM 64      // mlp rows per block
#define HP1 1032   // h1 LDS row stride (1024 + 8 pad) in bf16 (16B-aligned rows)
#define SCP2 36    // phase-C scratch row stride (32 + 4 pad) in bf16
#define WTP 68     // sage LDS weight row stride (64 + 4 pad) in f32

__device__ __forceinline__ u16 f2bf(float f) {
    unsigned int u = __float_as_uint(f);
    u = (u + 0x7FFFu + ((u >> 16) & 1u)) >> 16;   // RNE
    return (u16)u;
}

// ---------------- transpose + f32->bf16 convert: out[c][r] = in[r][c] ----------------
__global__ __launch_bounds__(256) void transpose_cvt(const float* __restrict__ in,
                                                     u16* __restrict__ out, int R, int C) {
    __shared__ float tile[32][33];
    int tx = threadIdx.x, ty = threadIdx.y;
    int cb = blockIdx.x * 32, rb = blockIdx.y * 32;
#pragma unroll
    for (int i = 0; i < 4; ++i) {
        int r = rb + ty + i * 8, c = cb + tx;
        tile[ty + i * 8][tx] = (r < R && c < C) ? in[(size_t)r * C + c] : 0.f;
    }
    __syncthreads();
#pragma unroll
    for (int i = 0; i < 4; ++i) {
        int c = cb + ty + i * 8, r = rb + tx;
        if (r < R && c < C) out[(size_t)c * R + r] = f2bf(tile[tx][ty + i * 8]);
    }
}

// ---------------- pack Wm2 [k=1024][n=1024] f32 -> per-(wave,t,j,lane) MFMA-fragment order, bf16 ----------------
__global__ __launch_bounds__(256) void pack_w2(const float* __restrict__ Wm2,
                                               u16* __restrict__ W2P) {
    int idx = blockIdx.x * 256 + threadIdx.x;   // 0 .. 131071
    int lane = idx & 63;
    int chunk = idx >> 6;           // w*128 + t*2 + j
    int j = chunk & 1;
    int t = (chunk >> 1) & 63;
    int w = chunk >> 7;             // 0..15
    int n = w * 64 + j * 32 + (lane & 31);
    int kbase = t * 16 + (lane >> 5) * 8;
    u16x8 tmp;
#pragma unroll
    for (int i = 0; i < 8; ++i) tmp[i] = f2bf(Wm2[(size_t)(kbase + i) * 1024 + n]);
    *(u16x8*)(W2P + (size_t)idx * 8) = tmp;
}

// ---------------- CSR build: histogram, multi-block scan, fill ----------------
__global__ __launch_bounds__(256) void hist_deg(const int* __restrict__ dst,
                                                int* __restrict__ deg, int E) {
    int i = blockIdx.x * 256 + threadIdx.x;
    int st = gridDim.x * 256;
    for (; i < E; i += st) atomicAdd(&deg[dst[i]], 1);
}

// per-block exclusive scan (1024 elems/block) + block totals
__global__ __launch_bounds__(1024) void scan_blk(const int* __restrict__ deg,
                                                 int* __restrict__ offs,
                                                 int* __restrict__ bsum, int N) {
    __shared__ int wsum[17];
    const int tid = threadIdx.x;
    const int lane = tid & 63;
    const int w = tid >> 6;
    const int idx = blockIdx.x * 1024 + tid;
    int v = (idx < N) ? deg[idx] : 0;
    int x = v;
#pragma unroll
    for (int d = 1; d < 64; d <<= 1) {
        int t = __shfl_up(x, d);
        if (lane >= d) x += t;
    }
    if (lane == 63) wsum[w + 1] = x;
    __syncthreads();
    if (tid == 0) {
        wsum[0] = 0;
        int s = 0;
#pragma unroll
        for (int i = 1; i <= 16; ++i) { s += wsum[i]; wsum[i] = s; }
        bsum[blockIdx.x] = s;
    }
    __syncthreads();
    if (idx < N) offs[idx] = wsum[w] + x - v;
}

// single-wave exclusive scan of block totals (nb <= a few hundred)
__global__ __launch_bounds__(64) void scan_top(int* __restrict__ bsum, int nb) {
    const int lane = threadIdx.x;
    int run = 0;
    for (int base = 0; base < nb; base += 64) {
        int idx = base + lane;
        int v = (idx < nb) ? bsum[idx] : 0;
        int x = v;
#pragma unroll
        for (int d = 1; d < 64; d <<= 1) {
            int t = __shfl_up(x, d);
            if (lane >= d) x += t;
        }
        if (idx < nb) bsum[idx] = run + x - v;
        run += __shfl(x, 63);
    }
}

__global__ __launch_bounds__(1024) void scan_add(int* __restrict__ offs,
                                                 const int* __restrict__ bsum, int N) {
    int idx = blockIdx.x * 1024 + threadIdx.x;
    if (idx < N) offs[idx] += bsum[blockIdx.x];
}

// fill: mutates offs[n] exclusive-start -> inclusive-end; eidx gets src ids
__global__ __launch_bounds__(256) void fill_csr(const int* __restrict__ src,
                                                const int* __restrict__ dst,
                                                int* __restrict__ offs,
                                                int* __restrict__ eidx, int E) {
    int i = blockIdx.x * 256 + threadIdx.x;
    int st = gridDim.x * 256;
    for (; i < E; i += st) {
        int pos = atomicAdd(&offs[dst[i]], 1);
        eidx[pos] = src[i];
    }
}

// ---------------- fused agg + SAGE: gather-mean (quarter-wave) -> per-wave LDS -> gemm.
// out = mean @ Wl + bl + xin @ Wr.  v6: gather unroll deepened 8 -> 16 (16 row-reads in
// flight per quarter-wave; the gather is the dominant latency chain at ~410 MB/layer).
template <int CO>
__global__ __launch_bounds__(256) void agg_sage(const f32x4* __restrict__ x4,
                                                const int* __restrict__ offs,
                                                const int* __restrict__ deg,
                                                const int* __restrict__ eidx,
                                                const float* __restrict__ Wl,
                                                const float* __restrict__ Wr,
                                                const float* __restrict__ bl,
                                                float* __restrict__ out,
                                                float* __restrict__ ssum,
                                                float* __restrict__ ssq, int N) {
    __shared__ float WlT[CO * WTP], WrT[CO * WTP];   // [c][k], padded stride
    __shared__ float rsum[4 * CO], rsq[4 * CO];
    __shared__ __align__(16) f32x4 meanLds[4][4][16]; // [wave][node][k4] = 4 KB
    for (int i = threadIdx.x; i < 64 * CO; i += 256) {
        int k = i / CO, c2 = i % CO;
        WlT[c2 * WTP + k] = Wl[i];
        WrT[c2 * WTP + k] = Wr[i];
    }
    __syncthreads();
    const int lane = threadIdx.x & 63;
    const int wv = threadIdx.x >> 6;
    const int q = lane >> 4, l16 = lane & 15;
    const int c = lane % CO;
    const int sub = lane / CO;
    const int wid = (blockIdx.x * 256 + threadIdx.x) >> 6;
    const int nw = (gridDim.x * 256) >> 6;
    const float bias = bl[c];
    const f32x4* wlrow = (const f32x4*)(WlT + c * WTP);
    const f32x4* wrrow = (const f32x4*)(WrT + c * WTP);
    constexpr int NB = (CO == 64) ? 4 : 2;
    const int bbase = (CO == 64) ? 0 : sub * 2;
    float lsum = 0.f, lsq = 0.f;
    for (int n0 = wid * 4; n0 < N; n0 += nw * 4) {
        // ---- gather phase: quarter-wave per node, 16-deep MLP
        {
            int n = n0 + q;
            bool valid = n < N;
            int end = valid ? offs[n] : 0;   // inclusive end after fill_csr
            int d = valid ? deg[n] : 0;
            int i = end - d;
            f32x4 s = {0.f, 0.f, 0.f, 0.f};
            for (; i + 16 <= end; i += 16) {
                int e[16];
#pragma unroll
                for (int u = 0; u < 16; ++u) e[u] = eidx[i + u];
                f32x4 v[16];
#pragma unroll
                for (int u = 0; u < 16; ++u) v[u] = x4[e[u] * 16 + l16];
                f32x4 s0 = ((v[0] + v[1]) + (v[2] + v[3])) + ((v[4] + v[5]) + (v[6] + v[7]));
                f32x4 s1 = ((v[8] + v[9]) + (v[10] + v[11])) + ((v[12] + v[13]) + (v[14] + v[15]));
                s = s + (s0 + s1);
            }
            for (; i + 8 <= end; i += 8) {
                int e0 = eidx[i],     e1 = eidx[i + 1], e2 = eidx[i + 2], e3 = eidx[i + 3];
                int e4 = eidx[i + 4], e5 = eidx[i + 5], e6 = eidx[i + 6], e7 = eidx[i + 7];
                f32x4 v0 = x4[e0 * 16 + l16];
                f32x4 v1 = x4[e1 * 16 + l16];
                f32x4 v2 = x4[e2 * 16 + l16];
                f32x4 v3 = x4[e3 * 16 + l16];
                f32x4 v4 = x4[e4 * 16 + l16];
                f32x4 v5 = x4[e5 * 16 + l16];
                f32x4 v6 = x4[e6 * 16 + l16];
                f32x4 v7 = x4[e7 * 16 + l16];
                s = s + ((v0 + v1) + (v2 + v3)) + ((v4 + v5) + (v6 + v7));
            }
            for (; i + 2 <= end; i += 2) {
                int e0 = eidx[i], e1 = eidx[i + 1];
                s = s + x4[e0 * 16 + l16] + x4[e1 * 16 + l16];
            }
            if (i < end) s = s + x4[eidx[i] * 16 + l16];
            float inv = 1.0f / fmaxf((float)d, 1.0f);
            f32x4 r = {s.x * inv, s.y * inv, s.z * inv, s.w * inv};
            meanLds[wv][q][l16] = r;
        }
        // ---- gemm phase (pa from LDS broadcast)
        float am[NB], ax[NB];
#pragma unroll
        for (int b = 0; b < NB; ++b) { am[b] = 0.f; ax[b] = 0.f; }
#pragma unroll 4
        for (int k4 = 0; k4 < 16; ++k4) {
            f32x4 wl = wlrow[k4];
            f32x4 wr = wrrow[k4];
#pragma unroll
            for (int b = 0; b < NB; ++b) {
                f32x4 pa = meanLds[wv][bbase + b][k4];
                f32x4 px = x4[(size_t)(n0 + bbase + b) * 16 + k4];
                am[b] += pa.x * wl.x + pa.y * wl.y + pa.z * wl.z + pa.w * wl.w;
                ax[b] += px.x * wr.x + px.y * wr.y + px.z * wr.z + px.w * wr.w;
            }
        }
#pragma unroll
        for (int b = 0; b < NB; ++b) {
            float v = am[b] + ax[b] + bias;
            out[(size_t)(n0 + bbase + b) * CO + c] = v;
            lsum += v; lsq += v * v;
        }
    }
    if (CO == 32) {
        lsum += __shfl_xor(lsum, 32);
        lsq  += __shfl_xor(lsq, 32);
    }
    if (sub == 0) { rsum[wv * CO + c] = lsum; rsq[wv * CO + c] = lsq; }
    __syncthreads();
    if (threadIdx.x < CO) {
        float s = rsum[threadIdx.x] + rsum[CO + threadIdx.x] +
                  rsum[2 * CO + threadIdx.x] + rsum[3 * CO + threadIdx.x];
        float q2 = rsq[threadIdx.x] + rsq[CO + threadIdx.x] +
                   rsq[2 * CO + threadIdx.x] + rsq[3 * CO + threadIdx.x];
        atomicAdd(&ssum[threadIdx.x], s);
        atomicAdd(&ssq[threadIdx.x], q2);
    }
}

// ---------------- BN (batch stats) + ReLU, in place; optional bf16 copy ----------------
template <int CO, int WRITE_BF>
__global__ __launch_bounds__(256) void bn_relu(float* __restrict__ data,
                                               const float* __restrict__ ssum,
                                               const float* __restrict__ ssq,
                                               const float* __restrict__ g,
                                               const float* __restrict__ be,
                                               u16* __restrict__ xb, int N) {
    const float invN = 1.0f / (float)N_NODES;
    int idx = blockIdx.x * 256 + threadIdx.x;
    int total = N * CO;
    int stride = gridDim.x * 256;
    for (; idx < total; idx += stride) {
        int c = idx & (CO - 1);
        float mu = ssum[c] * invN;
        float var = ssq[c] * invN - mu * mu;
        float sc = rsqrtf(var + 1e-5f) * g[c];
        float v = (data[idx] - mu) * sc + be[c];
        v = fmaxf(v, 0.f);
        data[idx] = v;
        if (WRITE_BF) xb[idx] = f2bf(v);
    }
}

// ---------------- fused MLP (v4 form): TM=64, 16 waves, wave owns 64 cols; Phase B = 32x32x16 MFMA,
// ---------------- B from fragment-packed W2P, prefetch depth 3, fully unrolled t-loop.
// ---------------- Phase A W1T/bias hoisted, Phase C b3 hoisted, setprio around MFMA quad.
__global__ __launch_bounds__(1024, 4) void mlp_fused(const u16* __restrict__ xt2b,   // [100032][32]
                                                     const u16* __restrict__ W1T,    // [1024][32]
                                                     const float* __restrict__ bm1,
                                                     const u16* __restrict__ W2P,    // packed, 2 MB
                                                     const float* __restrict__ bm2,
                                                     const u16* __restrict__ W3T,    // [16][1024]
                                                     const float* __restrict__ bm3,
                                                     float* __restrict__ probs,
                                                     float* __restrict__ logitsO) {
    __shared__ __align__(16) u16 h1s[TM * HP1];        // 132096 B (reused as f32 reduce buf)
    __shared__ __align__(16) u16 scr[16 * 16 * SCP2];  // 18432 B per-wave phase-C scratch
    const int tid = threadIdx.x;
    const int w = tid >> 6;          // 0..15
    const int lane = tid & 63;
    const int l16 = lane & 15;
    const int q = lane >> 4;
    const int m32 = lane & 31;       // 32x32 row/col index
    const int h8 = (lane >> 5) * 8;  // 32x32 k-offset
    const int row0 = blockIdx.x * TM;
    const int nb0 = w * 64;

    // per-wave packed-B stream base: chunk (t,j) at wq + (t*2+j)*512
    const u16* wq = W2P + (size_t)w * 128 * 512 + (size_t)lane * 8;

    // ---- B pipeline preload (t=0,1,2) — issued before Phase A to hide latency
    bf16x8 bp[3][2];
#pragma unroll
    for (int s = 0; s < 3; ++s)
#pragma unroll
        for (int j = 0; j < 2; ++j)
            bp[s][j] = *(const bf16x8*)(wq + (s * 2 + j) * 512);

    // ---- Phase A: h1 rows [row0,row0+64) = relu(xt2 @ Wm1 + bm1) -> LDS (wave fills its 64 cols)
    {
        bf16x8 bW[4];
        float biasA[4];
#pragma unroll
        for (int nt = 0; nt < 4; ++nt) {
            const int n = nb0 + nt * 16 + l16;
            bW[nt] = *(const bf16x8*)(W1T + n * 32 + q * 8);
            biasA[nt] = bm1[n];
        }
#pragma unroll
        for (int mt = 0; mt < 4; ++mt) {
            const int grow = row0 + mt * 16 + l16;               // < 100032 (1563*64)
            bf16x8 a = *(const bf16x8*)(xt2b + grow * 32 + q * 8);
#pragma unroll
            for (int nt = 0; nt < 4; ++nt) {
                const int n = nb0 + nt * 16 + l16;
                f32x4 c = {0.f, 0.f, 0.f, 0.f};
                c = __builtin_amdgcn_mfma_f32_16x16x32_bf16(a, bW[nt], c, 0, 0, 0);
#pragma unroll
                for (int r = 0; r < 4; ++r)
                    h1s[(mt * 16 + q * 4 + r) * HP1 + n] = f2bf(fmaxf(c[r] + biasA[nt], 0.f));
            }
        }
    }
    __syncthreads();

    // ---- Phase B: 64 k-steps of 16; wave computes 2x2 32x32 tiles; fully unrolled, depth-3 B pipe
    f32x16 acc[2][2];
#pragma unroll
    for (int i2 = 0; i2 < 2; ++i2)
#pragma unroll
        for (int j = 0; j < 2; ++j)
#pragma unroll
            for (int r = 0; r < 16; ++r) acc[i2][j][r] = 0.f;

#pragma unroll
    for (int t = 0; t < 64; ++t) {
        const int s = t % 3;
        const int k0 = t * 16;
        bf16x8 a0 = *(const bf16x8*)(h1s + (0 * 32 + m32) * HP1 + k0 + h8);
        bf16x8 a1 = *(const bf16x8*)(h1s + (1 * 32 + m32) * HP1 + k0 + h8);
        __builtin_amdgcn_s_setprio(1);
        acc[0][0] = __builtin_amdgcn_mfma_f32_32x32x16_bf16(a0, bp[s][0], acc[0][0], 0, 0, 0);
        acc[1][0] = __builtin_amdgcn_mfma_f32_32x32x16_bf16(a1, bp[s][0], acc[1][0], 0, 0, 0);
        acc[0][1] = __builtin_amdgcn_mfma_f32_32x32x16_bf16(a0, bp[s][1], acc[0][1], 0, 0, 0);
        acc[1][1] = __builtin_amdgcn_mfma_f32_32x32x16_bf16(a1, bp[s][1], acc[1][1], 0, 0, 0);
        __builtin_amdgcn_s_setprio(0);
        if (t + 3 < 64) {
            bp[s][0] = *(const bf16x8*)(wq + ((t + 3) * 2 + 0) * 512);
            bp[s][1] = *(const bf16x8*)(wq + ((t + 3) * 2 + 1) * 512);
        }
    }

    // ---- epilogue + Phase C: per 16x32 chunk -> scratch (A-layout) -> logits MFMA
    const float bias2[2] = { bm2[nb0 + m32], bm2[nb0 + 32 + m32] };
    bf16x8 b3f[2];
    b3f[0] = *(const bf16x8*)(W3T + l16 * 1024 + nb0 + 0 * 32 + q * 8);
    b3f[1] = *(const bf16x8*)(W3T + l16 * 1024 + nb0 + 1 * 32 + q * 8);
    f32x4 plog[4];
#pragma unroll
    for (int mt = 0; mt < 4; ++mt) plog[mt] = (f32x4){0.f, 0.f, 0.f, 0.f};
    u16* sw = scr + w * 16 * SCP2;

#pragma unroll
    for (int i2 = 0; i2 < 2; ++i2)
#pragma unroll
        for (int rh = 0; rh < 2; ++rh) {
            const int mt = i2 * 2 + rh;
#pragma unroll
            for (int j = 0; j < 2; ++j) {
#pragma unroll
                for (int rr = 0; rr < 8; ++rr) {
                    // 32x32 C-layout: row=(reg&3)+8*(reg>>2)+4*(lane>>5), col=lane&31
                    const int row16 = (rr & 3) + 8 * (rr >> 2) + 4 * (lane >> 5);
                    float v = acc[i2][j][rh * 8 + rr] + bias2[j];
                    sw[row16 * SCP2 + m32] = f2bf(fmaxf(v, 0.f));
                }
                bf16x8 a2 = *(const bf16x8*)(sw + l16 * SCP2 + q * 8);
                plog[mt] = __builtin_amdgcn_mfma_f32_16x16x32_bf16(a2, b3f[j], plog[mt], 0, 0, 0);
            }
        }

    // ---- cross-wave logit reduction (reuse h1s as f32 buffer: 16*4*64*16B = 64 KB)
    __syncthreads();
    f32x4* red = (f32x4*)h1s;
#pragma unroll
    for (int mt = 0; mt < 4; ++mt) red[(w * 4 + mt) * 64 + lane] = plog[mt];
    __syncthreads();

    if (w < 4) {                                   // wave w finalizes m-tile w
        f32x4 tot = red[w * 64 + lane];
#pragma unroll
        for (int w2 = 1; w2 < 16; ++w2) tot = tot + red[(w2 * 4 + w) * 64 + lane];
        const float b3v = bm3[l16];
#pragma unroll
        for (int r = 0; r < 4; ++r) {
            float v = tot[r] + b3v;
            float m = v;
            m = fmaxf(m, __shfl_xor(m, 1));
            m = fmaxf(m, __shfl_xor(m, 2));
            m = fmaxf(m, __shfl_xor(m, 4));
            m = fmaxf(m, __shfl_xor(m, 8));
            float e = __expf(v - m);
            float s = e;
            s += __shfl_xor(s, 1);
            s += __shfl_xor(s, 2);
            s += __shfl_xor(s, 4);
            s += __shfl_xor(s, 8);
            const int R = row0 + w * 16 + q * 4 + r;
            if (R < N_NODES) {
                logitsO[R * 16 + l16] = v;
                probs[R * 16 + l16] = e / s;
            }
        }
    }
}

extern "C" void kernel_launch(void* const* d_in, const int* in_sizes, int n_in,
                              void* d_out, int out_size, void* d_ws, size_t ws_size,
                              hipStream_t stream) {
    const float* x   = (const float*)d_in[0];
    const int*   ei  = (const int*)d_in[1];
    const int*   src = ei;
    const int*   dst = ei + N_EDGES;
    const float* W1l = (const float*)d_in[2];
    const float* b1l = (const float*)d_in[3];
    const float* W1r = (const float*)d_in[4];
    const float* g1  = (const float*)d_in[5];
    const float* be1 = (const float*)d_in[6];
    const float* W2l = (const float*)d_in[7];
    const float* b2l = (const float*)d_in[8];
    const float* W2r = (const float*)d_in[9];
    const float* g2  = (const float*)d_in[10];
    const float* be2 = (const float*)d_in[11];
    const float* Wm1 = (const float*)d_in[12];
    const float* bm1 = (const float*)d_in[13];
    const float* Wm2 = (const float*)d_in[14];
    const float* bm2 = (const float*)d_in[15];
    const float* Wm3 = (const float*)d_in[16];
    const float* bm3 = (const float*)d_in[17];

    float* probs  = (float*)d_out;                 // [N,16]
    float* logits = probs + 1600000;               // [N,16]
    float* xt1    = probs + 3200000;               // [N,64]
    float* xt2    = probs + 9600000;               // [N,32]

    char* wsb    = (char*)d_ws;
    int*  deg    = (int*)(wsb);                    //   400,000 B
    float* stats = (float*)(wsb + 400000);         //       768 B
    int*  offs   = (int*)(wsb + 400768);           //   400,000 B
    int*  eidx   = (int*)(wsb + 800768);           // 6,400,000 B
    int*  bsum   = (int*)(wsb + 7200768);          // scan block totals (dead after scan_add)
    u16*  xt2b   = (u16*)(wsb + 32800768);         // 6,402,048 B ([100032][32])
    u16*  W1T    = (u16*)(wsb + 39202816);         //    65,536 B
    u16*  W2P    = (u16*)(wsb + 39268352);         // 2,097,152 B (fragment-packed Wm2)
    u16*  W3T    = (u16*)(wsb + 41365504);         //    32,768 B  (end: 41,398,272)
    float* sum1 = stats, *sq1 = stats + 64, *sum2 = stats + 128, *sq2 = stats + 160;

    // zero deg + stats; zero xt2b tail rows 100000..100031
    hipMemsetAsync(wsb, 0, 400768, stream);
    hipMemsetAsync(xt2b + 100000 * 32, 0, 32 * 32 * sizeof(u16), stream);

    // weight transforms (bf16)
    transpose_cvt<<<dim3(32, 1),  dim3(32, 8), 0, stream>>>(Wm1, W1T, 32, 1024);
    pack_w2<<<512, 256, 0, stream>>>(Wm2, W2P);
    transpose_cvt<<<dim3(1, 32),  dim3(32, 8), 0, stream>>>(Wm3, W3T, 1024, 16);

    // ---- CSR build (once; reused by both layers)
    hist_deg<<<6250, 256, 0, stream>>>(dst, deg, N_EDGES);
    scan_blk<<<98, 1024, 0, stream>>>(deg, offs, bsum, N_NODES);
    scan_top<<<1, 64, 0, stream>>>(bsum, 98);
    scan_add<<<98, 1024, 0, stream>>>(offs, bsum, N_NODES);
    fill_csr<<<6250, 256, 0, stream>>>(src, dst, offs, eidx, N_EDGES);

    // ---- layer 1: fused gather-mean + SAGE gemm
    agg_sage<64><<<1024, 256, 0, stream>>>((const f32x4*)x, offs, deg, eidx,
                                           W1l, W1r, b1l, xt1, sum1, sq1, N_NODES);
    bn_relu<64, 0><<<4096, 256, 0, stream>>>(xt1, sum1, sq1, g1, be1, nullptr, N_NODES);

    // ---- layer 2: fused gather-mean + SAGE gemm
    agg_sage<32><<<1024, 256, 0, stream>>>((const f32x4*)xt1, offs, deg, eidx,
                                           W2l, W2r, b2l, xt2, sum2, sq2, N_NODES);
    bn_relu<32, 1><<<2048, 256, 0, stream>>>(xt2, sum2, sq2, g2, be2, xt2b, N_NODES);

    // ---- fused MLP + softmax
    mlp_fused<<<1563, 1024, 0, stream>>>(xt2b, W1T, bm1, W2P, bm2, W3T, bm3, probs, logits);
}

// Round 7
// 769.731 us; speedup vs baseline: 1.0982x; 1.0155x over previous
//
#include <hip/hip_runtime.h>

typedef unsigned short u16;
typedef unsigned short u16x4 __attribute__((ext_vector_type(4)));
typedef unsigned short u16x8 __attribute__((ext_vector_type(8)));
typedef __bf16 bf16x8 __attribute__((ext_vector_type(8)));
typedef float f32x4 __attribute__((ext_vector_type(4)));
typedef float f32x16 __attribute__((ext_vector_type(16)));

#define N_NODES 100000
#define N_EDGES 1600000
#define TM 64      // mlp rows per block
#define HP1 1032   // h1 LDS row stride (1024 + 8 pad) in bf16 (16B-aligned rows)
#define SCP2 36    // phase-C scratch row stride (32 + 4 pad) in bf16
#define WTP 68     // sage LDS weight row stride (64 + 4 pad) in f32

__device__ __forceinline__ u16 f2bf(float f) {
    unsigned int u = __float_as_uint(f);
    u = (u + 0x7FFFu + ((u >> 16) & 1u)) >> 16;   // RNE
    return (u16)u;
}

__device__ __forceinline__ f32x4 bf2f4(u16x4 h) {
    f32x4 r;
    r.x = __uint_as_float(((unsigned)h.x) << 16);
    r.y = __uint_as_float(((unsigned)h.y) << 16);
    r.z = __uint_as_float(((unsigned)h.z) << 16);
    r.w = __uint_as_float(((unsigned)h.w) << 16);
    return r;
}

// ---------------- f32 -> bf16 copy (8 elems/thread, one-shot) ----------------
__global__ __launch_bounds__(256) void cvt_bf16(const float* __restrict__ in,
                                                u16* __restrict__ out) {
    int idx = blockIdx.x * 256 + threadIdx.x;   // x8 elements
    f32x4 a = *(const f32x4*)(in + (size_t)idx * 8);
    f32x4 b = *(const f32x4*)(in + (size_t)idx * 8 + 4);
    u16x8 o;
    o[0] = f2bf(a.x); o[1] = f2bf(a.y); o[2] = f2bf(a.z); o[3] = f2bf(a.w);
    o[4] = f2bf(b.x); o[5] = f2bf(b.y); o[6] = f2bf(b.z); o[7] = f2bf(b.w);
    *(u16x8*)(out + (size_t)idx * 8) = o;
}

// ---------------- transpose + f32->bf16 convert: out[c][r] = in[r][c] ----------------
__global__ __launch_bounds__(256) void transpose_cvt(const float* __restrict__ in,
                                                     u16* __restrict__ out, int R, int C) {
    __shared__ float tile[32][33];
    int tx = threadIdx.x, ty = threadIdx.y;
    int cb = blockIdx.x * 32, rb = blockIdx.y * 32;
#pragma unroll
    for (int i = 0; i < 4; ++i) {
        int r = rb + ty + i * 8, c = cb + tx;
        tile[ty + i * 8][tx] = (r < R && c < C) ? in[(size_t)r * C + c] : 0.f;
    }
    __syncthreads();
#pragma unroll
    for (int i = 0; i < 4; ++i) {
        int c = cb + ty + i * 8, r = rb + tx;
        if (r < R && c < C) out[(size_t)c * R + r] = f2bf(tile[tx][ty + i * 8]);
    }
}

// ---------------- pack Wm2 [k=1024][n=1024] f32 -> per-(wave,t,j,lane) MFMA-fragment order, bf16 ----------------
__global__ __launch_bounds__(256) void pack_w2(const float* __restrict__ Wm2,
                                               u16* __restrict__ W2P) {
    int idx = blockIdx.x * 256 + threadIdx.x;   // 0 .. 131071
    int lane = idx & 63;
    int chunk = idx >> 6;           // w*128 + t*2 + j
    int j = chunk & 1;
    int t = (chunk >> 1) & 63;
    int w = chunk >> 7;             // 0..15
    int n = w * 64 + j * 32 + (lane & 31);
    int kbase = t * 16 + (lane >> 5) * 8;
    u16x8 tmp;
#pragma unroll
    for (int i = 0; i < 8; ++i) tmp[i] = f2bf(Wm2[(size_t)(kbase + i) * 1024 + n]);
    *(u16x8*)(W2P + (size_t)idx * 8) = tmp;
}

// ---------------- CSR build: histogram, multi-block scan, fill ----------------
__global__ __launch_bounds__(256) void hist_deg(const int* __restrict__ dst,
                                                int* __restrict__ deg, int E) {
    int i = blockIdx.x * 256 + threadIdx.x;
    int st = gridDim.x * 256;
    for (; i < E; i += st) atomicAdd(&deg[dst[i]], 1);
}

// per-block exclusive scan (1024 elems/block) + block totals
__global__ __launch_bounds__(1024) void scan_blk(const int* __restrict__ deg,
                                                 int* __restrict__ offs,
                                                 int* __restrict__ bsum, int N) {
    __shared__ int wsum[17];
    const int tid = threadIdx.x;
    const int lane = tid & 63;
    const int w = tid >> 6;
    const int idx = blockIdx.x * 1024 + tid;
    int v = (idx < N) ? deg[idx] : 0;
    int x = v;
#pragma unroll
    for (int d = 1; d < 64; d <<= 1) {
        int t = __shfl_up(x, d);
        if (lane >= d) x += t;
    }
    if (lane == 63) wsum[w + 1] = x;
    __syncthreads();
    if (tid == 0) {
        wsum[0] = 0;
        int s = 0;
#pragma unroll
        for (int i = 1; i <= 16; ++i) { s += wsum[i]; wsum[i] = s; }
        bsum[blockIdx.x] = s;
    }
    __syncthreads();
    if (idx < N) offs[idx] = wsum[w] + x - v;
}

// single-wave exclusive scan of block totals (nb <= a few hundred)
__global__ __launch_bounds__(64) void scan_top(int* __restrict__ bsum, int nb) {
    const int lane = threadIdx.x;
    int run = 0;
    for (int base = 0; base < nb; base += 64) {
        int idx = base + lane;
        int v = (idx < nb) ? bsum[idx] : 0;
        int x = v;
#pragma unroll
        for (int d = 1; d < 64; d <<= 1) {
            int t = __shfl_up(x, d);
            if (lane >= d) x += t;
        }
        if (idx < nb) bsum[idx] = run + x - v;
        run += __shfl(x, 63);
    }
}

__global__ __launch_bounds__(1024) void scan_add(int* __restrict__ offs,
                                                 const int* __restrict__ bsum, int N) {
    int idx = blockIdx.x * 1024 + threadIdx.x;
    if (idx < N) offs[idx] += bsum[blockIdx.x];
}

// fill: mutates offs[n] exclusive-start -> inclusive-end; eidx gets src ids
__global__ __launch_bounds__(256) void fill_csr(const int* __restrict__ src,
                                                const int* __restrict__ dst,
                                                int* __restrict__ offs,
                                                int* __restrict__ eidx, int E) {
    int i = blockIdx.x * 256 + threadIdx.x;
    int st = gridDim.x * 256;
    for (; i < E; i += st) {
        int pos = atomicAdd(&offs[dst[i]], 1);
        eidx[pos] = src[i];
    }
}

// ---------------- fused agg + SAGE: gather-mean (quarter-wave, bf16 rows) -> per-wave LDS -> gemm.
// out = mean @ Wl + bl + xin @ Wr.  v7: gather reads bf16 node rows (128 B = 2 cache lines
// vs 4 for f32) -- the gather is random-line-rate-bound, so halving lines ~halves its time.
// Accumulation stays f32; the root term xin @ Wr still reads the exact f32 tensor.
template <int CO>
__global__ __launch_bounds__(256) void agg_sage(const u16x4* __restrict__ xg4,  // bf16 [N][CO_in]
                                                const f32x4* __restrict__ x4,   // f32  [N][CO_in]
                                                const int* __restrict__ offs,
                                                const int* __restrict__ deg,
                                                const int* __restrict__ eidx,
                                                const float* __restrict__ Wl,
                                                const float* __restrict__ Wr,
                                                const float* __restrict__ bl,
                                                float* __restrict__ out,
                                                float* __restrict__ ssum,
                                                float* __restrict__ ssq, int N) {
    __shared__ float WlT[CO * WTP], WrT[CO * WTP];   // [c][k], padded stride
    __shared__ float rsum[4 * CO], rsq[4 * CO];
    __shared__ __align__(16) f32x4 meanLds[4][4][16]; // [wave][node][k4] = 4 KB
    for (int i = threadIdx.x; i < 64 * CO; i += 256) {
        int k = i / CO, c2 = i % CO;
        WlT[c2 * WTP + k] = Wl[i];
        WrT[c2 * WTP + k] = Wr[i];
    }
    __syncthreads();
    const int lane = threadIdx.x & 63;
    const int wv = threadIdx.x >> 6;
    const int q = lane >> 4, l16 = lane & 15;
    const int c = lane % CO;
    const int sub = lane / CO;
    const int wid = (blockIdx.x * 256 + threadIdx.x) >> 6;
    const int nw = (gridDim.x * 256) >> 6;
    const float bias = bl[c];
    const f32x4* wlrow = (const f32x4*)(WlT + c * WTP);
    const f32x4* wrrow = (const f32x4*)(WrT + c * WTP);
    constexpr int NB = (CO == 64) ? 4 : 2;
    const int bbase = (CO == 64) ? 0 : sub * 2;
    float lsum = 0.f, lsq = 0.f;
    for (int n0 = wid * 4; n0 < N; n0 += nw * 4) {
        // ---- gather phase: quarter-wave per node, bf16 rows, 16-deep MLP
        {
            int n = n0 + q;
            bool valid = n < N;
            int end = valid ? offs[n] : 0;   // inclusive end after fill_csr
            int d = valid ? deg[n] : 0;
            int i = end - d;
            f32x4 s = {0.f, 0.f, 0.f, 0.f};
            for (; i + 16 <= end; i += 16) {
                int e[16];
#pragma unroll
                for (int u = 0; u < 16; ++u) e[u] = eidx[i + u];
                u16x4 h[16];
#pragma unroll
                for (int u = 0; u < 16; ++u) h[u] = xg4[e[u] * 16 + l16];
                f32x4 s0 = ((bf2f4(h[0]) + bf2f4(h[1])) + (bf2f4(h[2]) + bf2f4(h[3]))) +
                           ((bf2f4(h[4]) + bf2f4(h[5])) + (bf2f4(h[6]) + bf2f4(h[7])));
                f32x4 s1 = ((bf2f4(h[8]) + bf2f4(h[9])) + (bf2f4(h[10]) + bf2f4(h[11]))) +
                           ((bf2f4(h[12]) + bf2f4(h[13])) + (bf2f4(h[14]) + bf2f4(h[15])));
                s = s + (s0 + s1);
            }
            for (; i + 8 <= end; i += 8) {
                int e0 = eidx[i],     e1 = eidx[i + 1], e2 = eidx[i + 2], e3 = eidx[i + 3];
                int e4 = eidx[i + 4], e5 = eidx[i + 5], e6 = eidx[i + 6], e7 = eidx[i + 7];
                u16x4 h0 = xg4[e0 * 16 + l16];
                u16x4 h1 = xg4[e1 * 16 + l16];
                u16x4 h2 = xg4[e2 * 16 + l16];
                u16x4 h3 = xg4[e3 * 16 + l16];
                u16x4 h4 = xg4[e4 * 16 + l16];
                u16x4 h5 = xg4[e5 * 16 + l16];
                u16x4 h6 = xg4[e6 * 16 + l16];
                u16x4 h7 = xg4[e7 * 16 + l16];
                s = s + ((bf2f4(h0) + bf2f4(h1)) + (bf2f4(h2) + bf2f4(h3))) +
                        ((bf2f4(h4) + bf2f4(h5)) + (bf2f4(h6) + bf2f4(h7)));
            }
            for (; i + 2 <= end; i += 2) {
                int e0 = eidx[i], e1 = eidx[i + 1];
                s = s + bf2f4(xg4[e0 * 16 + l16]) + bf2f4(xg4[e1 * 16 + l16]);
            }
            if (i < end) s = s + bf2f4(xg4[eidx[i] * 16 + l16]);
            float inv = 1.0f / fmaxf((float)d, 1.0f);
            f32x4 r = {s.x * inv, s.y * inv, s.z * inv, s.w * inv};
            meanLds[wv][q][l16] = r;
        }
        // ---- gemm phase (pa from LDS broadcast; px from exact f32 tensor)
        float am[NB], ax[NB];
#pragma unroll
        for (int b = 0; b < NB; ++b) { am[b] = 0.f; ax[b] = 0.f; }
#pragma unroll 4
        for (int k4 = 0; k4 < 16; ++k4) {
            f32x4 wl = wlrow[k4];
            f32x4 wr = wrrow[k4];
#pragma unroll
            for (int b = 0; b < NB; ++b) {
                f32x4 pa = meanLds[wv][bbase + b][k4];
                f32x4 px = x4[(size_t)(n0 + bbase + b) * 16 + k4];
                am[b] += pa.x * wl.x + pa.y * wl.y + pa.z * wl.z + pa.w * wl.w;
                ax[b] += px.x * wr.x + px.y * wr.y + px.z * wr.z + px.w * wr.w;
            }
        }
#pragma unroll
        for (int b = 0; b < NB; ++b) {
            float v = am[b] + ax[b] + bias;
            out[(size_t)(n0 + bbase + b) * CO + c] = v;
            lsum += v; lsq += v * v;
        }
    }
    if (CO == 32) {
        lsum += __shfl_xor(lsum, 32);
        lsq  += __shfl_xor(lsq, 32);
    }
    if (sub == 0) { rsum[wv * CO + c] = lsum; rsq[wv * CO + c] = lsq; }
    __syncthreads();
    if (threadIdx.x < CO) {
        float s = rsum[threadIdx.x] + rsum[CO + threadIdx.x] +
                  rsum[2 * CO + threadIdx.x] + rsum[3 * CO + threadIdx.x];
        float q2 = rsq[threadIdx.x] + rsq[CO + threadIdx.x] +
                   rsq[2 * CO + threadIdx.x] + rsq[3 * CO + threadIdx.x];
        atomicAdd(&ssum[threadIdx.x], s);
        atomicAdd(&ssq[threadIdx.x], q2);
    }
}

// ---------------- BN (batch stats) + ReLU, in place; optional bf16 copy ----------------
template <int CO, int WRITE_BF>
__global__ __launch_bounds__(256) void bn_relu(float* __restrict__ data,
                                               const float* __restrict__ ssum,
                                               const float* __restrict__ ssq,
                                               const float* __restrict__ g,
                                               const float* __restrict__ be,
                                               u16* __restrict__ xb, int N) {
    const float invN = 1.0f / (float)N_NODES;
    int idx = blockIdx.x * 256 + threadIdx.x;
    int total = N * CO;
    int stride = gridDim.x * 256;
    for (; idx < total; idx += stride) {
        int c = idx & (CO - 1);
        float mu = ssum[c] * invN;
        float var = ssq[c] * invN - mu * mu;
        float sc = rsqrtf(var + 1e-5f) * g[c];
        float v = (data[idx] - mu) * sc + be[c];
        v = fmaxf(v, 0.f);
        data[idx] = v;
        if (WRITE_BF) xb[idx] = f2bf(v);
    }
}

// ---------------- fused MLP (v4 form): TM=64, 16 waves, wave owns 64 cols; Phase B = 32x32x16 MFMA,
// ---------------- B from fragment-packed W2P, prefetch depth 3, fully unrolled t-loop.
// ---------------- Phase A W1T/bias hoisted, Phase C b3 hoisted, setprio around MFMA quad.
__global__ __launch_bounds__(1024, 4) void mlp_fused(const u16* __restrict__ xt2b,   // [100032][32]
                                                     const u16* __restrict__ W1T,    // [1024][32]
                                                     const float* __restrict__ bm1,
                                                     const u16* __restrict__ W2P,    // packed, 2 MB
                                                     const float* __restrict__ bm2,
                                                     const u16* __restrict__ W3T,    // [16][1024]
                                                     const float* __restrict__ bm3,
                                                     float* __restrict__ probs,
                                                     float* __restrict__ logitsO) {
    __shared__ __align__(16) u16 h1s[TM * HP1];        // 132096 B (reused as f32 reduce buf)
    __shared__ __align__(16) u16 scr[16 * 16 * SCP2];  // 18432 B per-wave phase-C scratch
    const int tid = threadIdx.x;
    const int w = tid >> 6;          // 0..15
    const int lane = tid & 63;
    const int l16 = lane & 15;
    const int q = lane >> 4;
    const int m32 = lane & 31;       // 32x32 row/col index
    const int h8 = (lane >> 5) * 8;  // 32x32 k-offset
    const int row0 = blockIdx.x * TM;
    const int nb0 = w * 64;

    // per-wave packed-B stream base: chunk (t,j) at wq + (t*2+j)*512
    const u16* wq = W2P + (size_t)w * 128 * 512 + (size_t)lane * 8;

    // ---- B pipeline preload (t=0,1,2) — issued before Phase A to hide latency
    bf16x8 bp[3][2];
#pragma unroll
    for (int s = 0; s < 3; ++s)
#pragma unroll
        for (int j = 0; j < 2; ++j)
            bp[s][j] = *(const bf16x8*)(wq + (s * 2 + j) * 512);

    // ---- Phase A: h1 rows [row0,row0+64) = relu(xt2 @ Wm1 + bm1) -> LDS (wave fills its 64 cols)
    {
        bf16x8 bW[4];
        float biasA[4];
#pragma unroll
        for (int nt = 0; nt < 4; ++nt) {
            const int n = nb0 + nt * 16 + l16;
            bW[nt] = *(const bf16x8*)(W1T + n * 32 + q * 8);
            biasA[nt] = bm1[n];
        }
#pragma unroll
        for (int mt = 0; mt < 4; ++mt) {
            const int grow = row0 + mt * 16 + l16;               // < 100032 (1563*64)
            bf16x8 a = *(const bf16x8*)(xt2b + grow * 32 + q * 8);
#pragma unroll
            for (int nt = 0; nt < 4; ++nt) {
                const int n = nb0 + nt * 16 + l16;
                f32x4 c = {0.f, 0.f, 0.f, 0.f};
                c = __builtin_amdgcn_mfma_f32_16x16x32_bf16(a, bW[nt], c, 0, 0, 0);
#pragma unroll
                for (int r = 0; r < 4; ++r)
                    h1s[(mt * 16 + q * 4 + r) * HP1 + n] = f2bf(fmaxf(c[r] + biasA[nt], 0.f));
            }
        }
    }
    __syncthreads();

    // ---- Phase B: 64 k-steps of 16; wave computes 2x2 32x32 tiles; fully unrolled, depth-3 B pipe
    f32x16 acc[2][2];
#pragma unroll
    for (int i2 = 0; i2 < 2; ++i2)
#pragma unroll
        for (int j = 0; j < 2; ++j)
#pragma unroll
            for (int r = 0; r < 16; ++r) acc[i2][j][r] = 0.f;

#pragma unroll
    for (int t = 0; t < 64; ++t) {
        const int s = t % 3;
        const int k0 = t * 16;
        bf16x8 a0 = *(const bf16x8*)(h1s + (0 * 32 + m32) * HP1 + k0 + h8);
        bf16x8 a1 = *(const bf16x8*)(h1s + (1 * 32 + m32) * HP1 + k0 + h8);
        __builtin_amdgcn_s_setprio(1);
        acc[0][0] = __builtin_amdgcn_mfma_f32_32x32x16_bf16(a0, bp[s][0], acc[0][0], 0, 0, 0);
        acc[1][0] = __builtin_amdgcn_mfma_f32_32x32x16_bf16(a1, bp[s][0], acc[1][0], 0, 0, 0);
        acc[0][1] = __builtin_amdgcn_mfma_f32_32x32x16_bf16(a0, bp[s][1], acc[0][1], 0, 0, 0);
        acc[1][1] = __builtin_amdgcn_mfma_f32_32x32x16_bf16(a1, bp[s][1], acc[1][1], 0, 0, 0);
        __builtin_amdgcn_s_setprio(0);
        if (t + 3 < 64) {
            bp[s][0] = *(const bf16x8*)(wq + ((t + 3) * 2 + 0) * 512);
            bp[s][1] = *(const bf16x8*)(wq + ((t + 3) * 2 + 1) * 512);
        }
    }

    // ---- epilogue + Phase C: per 16x32 chunk -> scratch (A-layout) -> logits MFMA
    const float bias2[2] = { bm2[nb0 + m32], bm2[nb0 + 32 + m32] };
    bf16x8 b3f[2];
    b3f[0] = *(const bf16x8*)(W3T + l16 * 1024 + nb0 + 0 * 32 + q * 8);
    b3f[1] = *(const bf16x8*)(W3T + l16 * 1024 + nb0 + 1 * 32 + q * 8);
    f32x4 plog[4];
#pragma unroll
    for (int mt = 0; mt < 4; ++mt) plog[mt] = (f32x4){0.f, 0.f, 0.f, 0.f};
    u16* sw = scr + w * 16 * SCP2;

#pragma unroll
    for (int i2 = 0; i2 < 2; ++i2)
#pragma unroll
        for (int rh = 0; rh < 2; ++rh) {
            const int mt = i2 * 2 + rh;
#pragma unroll
            for (int j = 0; j < 2; ++j) {
#pragma unroll
                for (int rr = 0; rr < 8; ++rr) {
                    // 32x32 C-layout: row=(reg&3)+8*(reg>>2)+4*(lane>>5), col=lane&31
                    const int row16 = (rr & 3) + 8 * (rr >> 2) + 4 * (lane >> 5);
                    float v = acc[i2][j][rh * 8 + rr] + bias2[j];
                    sw[row16 * SCP2 + m32] = f2bf(fmaxf(v, 0.f));
                }
                bf16x8 a2 = *(const bf16x8*)(sw + l16 * SCP2 + q * 8);
                plog[mt] = __builtin_amdgcn_mfma_f32_16x16x32_bf16(a2, b3f[j], plog[mt], 0, 0, 0);
            }
        }

    // ---- cross-wave logit reduction (reuse h1s as f32 buffer: 16*4*64*16B = 64 KB)
    __syncthreads();
    f32x4* red = (f32x4*)h1s;
#pragma unroll
    for (int mt = 0; mt < 4; ++mt) red[(w * 4 + mt) * 64 + lane] = plog[mt];
    __syncthreads();

    if (w < 4) {                                   // wave w finalizes m-tile w
        f32x4 tot = red[w * 64 + lane];
#pragma unroll
        for (int w2 = 1; w2 < 16; ++w2) tot = tot + red[(w2 * 4 + w) * 64 + lane];
        const float b3v = bm3[l16];
#pragma unroll
        for (int r = 0; r < 4; ++r) {
            float v = tot[r] + b3v;
            float m = v;
            m = fmaxf(m, __shfl_xor(m, 1));
            m = fmaxf(m, __shfl_xor(m, 2));
            m = fmaxf(m, __shfl_xor(m, 4));
            m = fmaxf(m, __shfl_xor(m, 8));
            float e = __expf(v - m);
            float s = e;
            s += __shfl_xor(s, 1);
            s += __shfl_xor(s, 2);
            s += __shfl_xor(s, 4);
            s += __shfl_xor(s, 8);
            const int R = row0 + w * 16 + q * 4 + r;
            if (R < N_NODES) {
                logitsO[R * 16 + l16] = v;
                probs[R * 16 + l16] = e / s;
            }
        }
    }
}

extern "C" void kernel_launch(void* const* d_in, const int* in_sizes, int n_in,
                              void* d_out, int out_size, void* d_ws, size_t ws_size,
                              hipStream_t stream) {
    const float* x   = (const float*)d_in[0];
    const int*   ei  = (const int*)d_in[1];
    const int*   src = ei;
    const int*   dst = ei + N_EDGES;
    const float* W1l = (const float*)d_in[2];
    const float* b1l = (const float*)d_in[3];
    const float* W1r = (const float*)d_in[4];
    const float* g1  = (const float*)d_in[5];
    const float* be1 = (const float*)d_in[6];
    const float* W2l = (const float*)d_in[7];
    const float* b2l = (const float*)d_in[8];
    const float* W2r = (const float*)d_in[9];
    const float* g2  = (const float*)d_in[10];
    const float* be2 = (const float*)d_in[11];
    const float* Wm1 = (const float*)d_in[12];
    const float* bm1 = (const float*)d_in[13];
    const float* Wm2 = (const float*)d_in[14];
    const float* bm2 = (const float*)d_in[15];
    const float* Wm3 = (const float*)d_in[16];
    const float* bm3 = (const float*)d_in[17];

    float* probs  = (float*)d_out;                 // [N,16]
    float* logits = probs + 1600000;               // [N,16]
    float* xt1    = probs + 3200000;               // [N,64]
    float* xt2    = probs + 9600000;               // [N,32]

    char* wsb    = (char*)d_ws;
    int*  deg    = (int*)(wsb);                    //   400,000 B
    float* stats = (float*)(wsb + 400000);         //       768 B
    int*  offs   = (int*)(wsb + 400768);           //   400,000 B
    int*  eidx   = (int*)(wsb + 800768);           // 6,400,000 B (ends 7,200,768)
    u16*  xb1    = (u16*)(wsb + 7200768);          // 12,800,000 B bf16 x   (ends 20,000,768)
    u16*  xt1b   = (u16*)(wsb + 20000768);         // 12,800,000 B bf16 xt1 (ends 32,800,768)
    u16*  xt2b   = (u16*)(wsb + 32800768);         // 6,402,048 B ([100032][32])
    u16*  W1T    = (u16*)(wsb + 39202816);         //    65,536 B
    u16*  W2P    = (u16*)(wsb + 39268352);         // 2,097,152 B (fragment-packed Wm2)
    u16*  W3T    = (u16*)(wsb + 41365504);         //    32,768 B  (ends 41,398,272)
    int*  bsum   = (int*)(wsb + 41398272);         //       400 B scan block totals
    float* sum1 = stats, *sq1 = stats + 64, *sum2 = stats + 128, *sq2 = stats + 160;

    // zero deg + stats; zero xt2b tail rows 100000..100031
    hipMemsetAsync(wsb, 0, 400768, stream);
    hipMemsetAsync(xt2b + 100000 * 32, 0, 32 * 32 * sizeof(u16), stream);

    // weight transforms (bf16) + bf16 copy of x (6.4M elems = 3125 blocks x 256 thr x 8)
    cvt_bf16<<<3125, 256, 0, stream>>>(x, xb1);
    transpose_cvt<<<dim3(32, 1),  dim3(32, 8), 0, stream>>>(Wm1, W1T, 32, 1024);
    pack_w2<<<512, 256, 0, stream>>>(Wm2, W2P);
    transpose_cvt<<<dim3(1, 32),  dim3(32, 8), 0, stream>>>(Wm3, W3T, 1024, 16);

    // ---- CSR build (once; reused by both layers)
    hist_deg<<<6250, 256, 0, stream>>>(dst, deg, N_EDGES);
    scan_blk<<<98, 1024, 0, stream>>>(deg, offs, bsum, N_NODES);
    scan_top<<<1, 64, 0, stream>>>(bsum, 98);
    scan_add<<<98, 1024, 0, stream>>>(offs, bsum, N_NODES);
    fill_csr<<<6250, 256, 0, stream>>>(src, dst, offs, eidx, N_EDGES);

    // ---- layer 1: fused gather-mean (bf16 rows) + SAGE gemm
    agg_sage<64><<<1024, 256, 0, stream>>>((const u16x4*)xb1, (const f32x4*)x,
                                           offs, deg, eidx,
                                           W1l, W1r, b1l, xt1, sum1, sq1, N_NODES);
    bn_relu<64, 1><<<4096, 256, 0, stream>>>(xt1, sum1, sq1, g1, be1, xt1b, N_NODES);

    // ---- layer 2: fused gather-mean (bf16 rows) + SAGE gemm
    agg_sage<32><<<1024, 256, 0, stream>>>((const u16x4*)xt1b, (const f32x4*)xt1,
                                           offs, deg, eidx,
                                           W2l, W2r, b2l, xt2, sum2, sq2, N_NODES);
    bn_relu<32, 1><<<2048, 256, 0, stream>>>(xt2, sum2, sq2, g2, be2, xt2b, N_NODES);

    // ---- fused MLP + softmax
    mlp_fused<<<1563, 1024, 0, stream>>>(xt2b, W1T, bm1, W2P, bm2, W3T, bm3, probs, logits);
}

// Round 8
// 731.640 us; speedup vs baseline: 1.1554x; 1.0521x over previous
//
#include <hip/hip_runtime.h>

typedef unsigned short u16;
typedef unsigned short u16x4 __attribute__((ext_vector_type(4)));
typedef unsigned short u16x8 __attribute__((ext_vector_type(8)));
typedef __bf16 bf16x8 __attribute__((ext_vector_type(8)));
typedef float f32x4 __attribute__((ext_vector_type(4)));
typedef float f32x16 __attribute__((ext_vector_type(16)));

#define N_NODES 100000
#define N_EDGES 1600000
#define TM 64      // mlp rows per block
#define HP1 1032   // h1 LDS row stride (1024 + 8 pad) in bf16 (16B-aligned rows)
#define SCP2 36    // phase-C scratch row stride (32 + 4 pad) in bf16
#define WTP 68     // sage LDS weight row stride (64 + 4 pad) in f32
#define MLP2 68    // mean LDS row stride in f32 (64 + 4 pad, keeps f32x4 alignment)

__device__ __forceinline__ u16 f2bf(float f) {
    unsigned int u = __float_as_uint(f);
    u = (u + 0x7FFFu + ((u >> 16) & 1u)) >> 16;   // RNE
    return (u16)u;
}

__device__ __forceinline__ void bf2f8(u16x8 h, f32x4& lo, f32x4& hi) {
    lo.x = __uint_as_float(((unsigned)h[0]) << 16);
    lo.y = __uint_as_float(((unsigned)h[1]) << 16);
    lo.z = __uint_as_float(((unsigned)h[2]) << 16);
    lo.w = __uint_as_float(((unsigned)h[3]) << 16);
    hi.x = __uint_as_float(((unsigned)h[4]) << 16);
    hi.y = __uint_as_float(((unsigned)h[5]) << 16);
    hi.z = __uint_as_float(((unsigned)h[6]) << 16);
    hi.w = __uint_as_float(((unsigned)h[7]) << 16);
}

// ---------------- f32 -> bf16 copy (8 elems/thread, one-shot) ----------------
__global__ __launch_bounds__(256) void cvt_bf16(const float* __restrict__ in,
                                                u16* __restrict__ out) {
    int idx = blockIdx.x * 256 + threadIdx.x;   // x8 elements
    f32x4 a = *(const f32x4*)(in + (size_t)idx * 8);
    f32x4 b = *(const f32x4*)(in + (size_t)idx * 8 + 4);
    u16x8 o;
    o[0] = f2bf(a.x); o[1] = f2bf(a.y); o[2] = f2bf(a.z); o[3] = f2bf(a.w);
    o[4] = f2bf(b.x); o[5] = f2bf(b.y); o[6] = f2bf(b.z); o[7] = f2bf(b.w);
    *(u16x8*)(out + (size_t)idx * 8) = o;
}

// ---------------- transpose + f32->bf16 convert: out[c][r] = in[r][c] ----------------
__global__ __launch_bounds__(256) void transpose_cvt(const float* __restrict__ in,
                                                     u16* __restrict__ out, int R, int C) {
    __shared__ float tile[32][33];
    int tx = threadIdx.x, ty = threadIdx.y;
    int cb = blockIdx.x * 32, rb = blockIdx.y * 32;
#pragma unroll
    for (int i = 0; i < 4; ++i) {
        int r = rb + ty + i * 8, c = cb + tx;
        tile[ty + i * 8][tx] = (r < R && c < C) ? in[(size_t)r * C + c] : 0.f;
    }
    __syncthreads();
#pragma unroll
    for (int i = 0; i < 4; ++i) {
        int c = cb + ty + i * 8, r = rb + tx;
        if (r < R && c < C) out[(size_t)c * R + r] = f2bf(tile[tx][ty + i * 8]);
    }
}

// ---------------- pack Wm2 [k=1024][n=1024] f32 -> per-(wave,t,j,lane) MFMA-fragment order, bf16 ----------------
__global__ __launch_bounds__(256) void pack_w2(const float* __restrict__ Wm2,
                                               u16* __restrict__ W2P) {
    int idx = blockIdx.x * 256 + threadIdx.x;   // 0 .. 131071
    int lane = idx & 63;
    int chunk = idx >> 6;           // w*128 + t*2 + j
    int j = chunk & 1;
    int t = (chunk >> 1) & 63;
    int w = chunk >> 7;             // 0..15
    int n = w * 64 + j * 32 + (lane & 31);
    int kbase = t * 16 + (lane >> 5) * 8;
    u16x8 tmp;
#pragma unroll
    for (int i = 0; i < 8; ++i) tmp[i] = f2bf(Wm2[(size_t)(kbase + i) * 1024 + n]);
    *(u16x8*)(W2P + (size_t)idx * 8) = tmp;
}

// ---------------- CSR build: histogram, multi-block scan, fill ----------------
__global__ __launch_bounds__(256) void hist_deg(const int* __restrict__ dst,
                                                int* __restrict__ deg, int E) {
    int i = blockIdx.x * 256 + threadIdx.x;
    int st = gridDim.x * 256;
    for (; i < E; i += st) atomicAdd(&deg[dst[i]], 1);
}

// per-block exclusive scan (1024 elems/block) + block totals
__global__ __launch_bounds__(1024) void scan_blk(const int* __restrict__ deg,
                                                 int* __restrict__ offs,
                                                 int* __restrict__ bsum, int N) {
    __shared__ int wsum[17];
    const int tid = threadIdx.x;
    const int lane = tid & 63;
    const int w = tid >> 6;
    const int idx = blockIdx.x * 1024 + tid;
    int v = (idx < N) ? deg[idx] : 0;
    int x = v;
#pragma unroll
    for (int d = 1; d < 64; d <<= 1) {
        int t = __shfl_up(x, d);
        if (lane >= d) x += t;
    }
    if (lane == 63) wsum[w + 1] = x;
    __syncthreads();
    if (tid == 0) {
        wsum[0] = 0;
        int s = 0;
#pragma unroll
        for (int i = 1; i <= 16; ++i) { s += wsum[i]; wsum[i] = s; }
        bsum[blockIdx.x] = s;
    }
    __syncthreads();
    if (idx < N) offs[idx] = wsum[w] + x - v;
}

// single-wave exclusive scan of block totals (nb <= a few hundred)
__global__ __launch_bounds__(64) void scan_top(int* __restrict__ bsum, int nb) {
    const int lane = threadIdx.x;
    int run = 0;
    for (int base = 0; base < nb; base += 64) {
        int idx = base + lane;
        int v = (idx < nb) ? bsum[idx] : 0;
        int x = v;
#pragma unroll
        for (int d = 1; d < 64; d <<= 1) {
            int t = __shfl_up(x, d);
            if (lane >= d) x += t;
        }
        if (idx < nb) bsum[idx] = run + x - v;
        run += __shfl(x, 63);
    }
}

__global__ __launch_bounds__(1024) void scan_add(int* __restrict__ offs,
                                                 const int* __restrict__ bsum, int N) {
    int idx = blockIdx.x * 1024 + threadIdx.x;
    if (idx < N) offs[idx] += bsum[blockIdx.x];
}

// fill: mutates offs[n] exclusive-start -> inclusive-end; eidx gets src ids
__global__ __launch_bounds__(256) void fill_csr(const int* __restrict__ src,
                                                const int* __restrict__ dst,
                                                int* __restrict__ offs,
                                                int* __restrict__ eidx, int E) {
    int i = blockIdx.x * 256 + threadIdx.x;
    int st = gridDim.x * 256;
    for (; i < E; i += st) {
        int pos = atomicAdd(&offs[dst[i]], 1);
        eidx[pos] = src[i];
    }
}

// ---------------- fused agg + SAGE v8: 8 nodes per wave-group.
// Gather: eighth-wave (8 lanes x u16x8 = one 128-B bf16 row) -> one gather instruction
// serves 8 nodes (2x v7's 4). Gemm: NB=8 (CO=64) / NB=4 x 2 subs (CO=32) -> each
// LDS weight sweep + loop overhead amortized over 8 nodes (2x v7).
// Accumulation stays f32; root term xin @ Wr reads the exact f32 tensor.
template <int CO>
__global__ __launch_bounds__(256) void agg_sage(const u16x8* __restrict__ xg8,  // bf16 [N][64]
                                                const f32x4* __restrict__ x4,   // f32  [N][64]
                                                const int* __restrict__ offs,
                                                const int* __restrict__ deg,
                                                const int* __restrict__ eidx,
                                                const float* __restrict__ Wl,
                                                const float* __restrict__ Wr,
                                                const float* __restrict__ bl,
                                                float* __restrict__ out,
                                                float* __restrict__ ssum,
                                                float* __restrict__ ssq, int N) {
    __shared__ float WlT[CO * WTP], WrT[CO * WTP];   // [c][k], padded stride
    __shared__ float rsum[4 * CO], rsq[4 * CO];
    __shared__ float mlds[4][8][MLP2];               // [wave][node][64+pad] mean rows, 8.7 KB
    for (int i = threadIdx.x; i < 64 * CO; i += 256) {
        int k = i / CO, c2 = i % CO;
        WlT[c2 * WTP + k] = Wl[i];
        WrT[c2 * WTP + k] = Wr[i];
    }
    __syncthreads();
    const int lane = threadIdx.x & 63;
    const int wv = threadIdx.x >> 6;
    const int o = lane >> 3;          // node slot 0..7
    const int l8 = lane & 7;          // 16-B segment within the 128-B row
    const int c = lane % CO;
    const int sub = lane / CO;
    const int wid = (blockIdx.x * 256 + threadIdx.x) >> 6;
    const int nw = (gridDim.x * 256) >> 6;
    const float bias = bl[c];
    const f32x4* wlrow = (const f32x4*)(WlT + c * WTP);
    const f32x4* wrrow = (const f32x4*)(WrT + c * WTP);
    constexpr int NB = (CO == 64) ? 8 : 4;
    const int bbase = (CO == 64) ? 0 : sub * 4;
    float lsum = 0.f, lsq = 0.f;
    for (int n0 = wid * 8; n0 < N; n0 += nw * 8) {
        // ---- gather phase: eighth-wave per node (8 nodes/wave), 8-deep
        {
            int n = n0 + o;
            bool valid = n < N;
            int end = valid ? offs[n] : 0;   // inclusive end after fill_csr
            int d = valid ? deg[n] : 0;
            int i = end - d;
            f32x4 slo = {0.f, 0.f, 0.f, 0.f}, shi = {0.f, 0.f, 0.f, 0.f};
            for (; i + 8 <= end; i += 8) {
                int e[8];
#pragma unroll
                for (int u = 0; u < 8; ++u) e[u] = eidx[i + u];
                u16x8 h[8];
#pragma unroll
                for (int u = 0; u < 8; ++u) h[u] = xg8[(size_t)e[u] * 8 + l8];
                f32x4 lo[8], hi[8];
#pragma unroll
                for (int u = 0; u < 8; ++u) bf2f8(h[u], lo[u], hi[u]);
                slo = slo + (((lo[0] + lo[1]) + (lo[2] + lo[3])) +
                             ((lo[4] + lo[5]) + (lo[6] + lo[7])));
                shi = shi + (((hi[0] + hi[1]) + (hi[2] + hi[3])) +
                             ((hi[4] + hi[5]) + (hi[6] + hi[7])));
            }
            for (; i + 2 <= end; i += 2) {
                u16x8 h0 = xg8[(size_t)eidx[i] * 8 + l8];
                u16x8 h1 = xg8[(size_t)eidx[i + 1] * 8 + l8];
                f32x4 l0, h0f, l1, h1f;
                bf2f8(h0, l0, h0f);
                bf2f8(h1, l1, h1f);
                slo = slo + (l0 + l1);
                shi = shi + (h0f + h1f);
            }
            if (i < end) {
                u16x8 h0 = xg8[(size_t)eidx[i] * 8 + l8];
                f32x4 l0, h0f;
                bf2f8(h0, l0, h0f);
                slo = slo + l0;
                shi = shi + h0f;
            }
            float inv = 1.0f / fmaxf((float)d, 1.0f);
            float* mrow = &mlds[wv][o][l8 * 8];
            f32x4 rlo = {slo.x * inv, slo.y * inv, slo.z * inv, slo.w * inv};
            f32x4 rhi = {shi.x * inv, shi.y * inv, shi.z * inv, shi.w * inv};
            *(f32x4*)(mrow) = rlo;
            *(f32x4*)(mrow + 4) = rhi;
        }
        // ---- gemm phase (pa from LDS broadcast; px from exact f32 tensor)
        float am[NB], ax[NB];
#pragma unroll
        for (int b = 0; b < NB; ++b) { am[b] = 0.f; ax[b] = 0.f; }
#pragma unroll 4
        for (int k4 = 0; k4 < 16; ++k4) {
            f32x4 wl = wlrow[k4];
            f32x4 wr = wrrow[k4];
#pragma unroll
            for (int b = 0; b < NB; ++b) {
                f32x4 pa = *(const f32x4*)&mlds[wv][bbase + b][k4 * 4];
                f32x4 px = x4[(size_t)(n0 + bbase + b) * 16 + k4];
                am[b] += pa.x * wl.x + pa.y * wl.y + pa.z * wl.z + pa.w * wl.w;
                ax[b] += px.x * wr.x + px.y * wr.y + px.z * wr.z + px.w * wr.w;
            }
        }
#pragma unroll
        for (int b = 0; b < NB; ++b) {
            float v = am[b] + ax[b] + bias;
            out[(size_t)(n0 + bbase + b) * CO + c] = v;
            lsum += v; lsq += v * v;
        }
    }
    if (CO == 32) {
        lsum += __shfl_xor(lsum, 32);
        lsq  += __shfl_xor(lsq, 32);
    }
    if (sub == 0) { rsum[wv * CO + c] = lsum; rsq[wv * CO + c] = lsq; }
    __syncthreads();
    if (threadIdx.x < CO) {
        float s = rsum[threadIdx.x] + rsum[CO + threadIdx.x] +
                  rsum[2 * CO + threadIdx.x] + rsum[3 * CO + threadIdx.x];
        float q2 = rsq[threadIdx.x] + rsq[CO + threadIdx.x] +
                   rsq[2 * CO + threadIdx.x] + rsq[3 * CO + threadIdx.x];
        atomicAdd(&ssum[threadIdx.x], s);
        atomicAdd(&ssq[threadIdx.x], q2);
    }
}

// ---------------- BN (batch stats) + ReLU, in place; optional bf16 copy ----------------
template <int CO, int WRITE_BF>
__global__ __launch_bounds__(256) void bn_relu(float* __restrict__ data,
                                               const float* __restrict__ ssum,
                                               const float* __restrict__ ssq,
                                               const float* __restrict__ g,
                                               const float* __restrict__ be,
                                               u16* __restrict__ xb, int N) {
    const float invN = 1.0f / (float)N_NODES;
    int idx = blockIdx.x * 256 + threadIdx.x;
    int total = N * CO;
    int stride = gridDim.x * 256;
    for (; idx < total; idx += stride) {
        int c = idx & (CO - 1);
        float mu = ssum[c] * invN;
        float var = ssq[c] * invN - mu * mu;
        float sc = rsqrtf(var + 1e-5f) * g[c];
        float v = (data[idx] - mu) * sc + be[c];
        v = fmaxf(v, 0.f);
        data[idx] = v;
        if (WRITE_BF) xb[idx] = f2bf(v);
    }
}

// ---------------- fused MLP (v4 form): TM=64, 16 waves, wave owns 64 cols; Phase B = 32x32x16 MFMA,
// ---------------- B from fragment-packed W2P, prefetch depth 3, fully unrolled t-loop.
// ---------------- Phase A W1T/bias hoisted, Phase C b3 hoisted, setprio around MFMA quad.
__global__ __launch_bounds__(1024, 4) void mlp_fused(const u16* __restrict__ xt2b,   // [100032][32]
                                                     const u16* __restrict__ W1T,    // [1024][32]
                                                     const float* __restrict__ bm1,
                                                     const u16* __restrict__ W2P,    // packed, 2 MB
                                                     const float* __restrict__ bm2,
                                                     const u16* __restrict__ W3T,    // [16][1024]
                                                     const float* __restrict__ bm3,
                                                     float* __restrict__ probs,
                                                     float* __restrict__ logitsO) {
    __shared__ __align__(16) u16 h1s[TM * HP1];        // 132096 B (reused as f32 reduce buf)
    __shared__ __align__(16) u16 scr[16 * 16 * SCP2];  // 18432 B per-wave phase-C scratch
    const int tid = threadIdx.x;
    const int w = tid >> 6;          // 0..15
    const int lane = tid & 63;
    const int l16 = lane & 15;
    const int q = lane >> 4;
    const int m32 = lane & 31;       // 32x32 row/col index
    const int h8 = (lane >> 5) * 8;  // 32x32 k-offset
    const int row0 = blockIdx.x * TM;
    const int nb0 = w * 64;

    // per-wave packed-B stream base: chunk (t,j) at wq + (t*2+j)*512
    const u16* wq = W2P + (size_t)w * 128 * 512 + (size_t)lane * 8;

    // ---- B pipeline preload (t=0,1,2) — issued before Phase A to hide latency
    bf16x8 bp[3][2];
#pragma unroll
    for (int s = 0; s < 3; ++s)
#pragma unroll
        for (int j = 0; j < 2; ++j)
            bp[s][j] = *(const bf16x8*)(wq + (s * 2 + j) * 512);

    // ---- Phase A: h1 rows [row0,row0+64) = relu(xt2 @ Wm1 + bm1) -> LDS (wave fills its 64 cols)
    {
        bf16x8 bW[4];
        float biasA[4];
#pragma unroll
        for (int nt = 0; nt < 4; ++nt) {
            const int n = nb0 + nt * 16 + l16;
            bW[nt] = *(const bf16x8*)(W1T + n * 32 + q * 8);
            biasA[nt] = bm1[n];
        }
#pragma unroll
        for (int mt = 0; mt < 4; ++mt) {
            const int grow = row0 + mt * 16 + l16;               // < 100032 (1563*64)
            bf16x8 a = *(const bf16x8*)(xt2b + grow * 32 + q * 8);
#pragma unroll
            for (int nt = 0; nt < 4; ++nt) {
                const int n = nb0 + nt * 16 + l16;
                f32x4 c = {0.f, 0.f, 0.f, 0.f};
                c = __builtin_amdgcn_mfma_f32_16x16x32_bf16(a, bW[nt], c, 0, 0, 0);
#pragma unroll
                for (int r = 0; r < 4; ++r)
                    h1s[(mt * 16 + q * 4 + r) * HP1 + n] = f2bf(fmaxf(c[r] + biasA[nt], 0.f));
            }
        }
    }
    __syncthreads();

    // ---- Phase B: 64 k-steps of 16; wave computes 2x2 32x32 tiles; fully unrolled, depth-3 B pipe
    f32x16 acc[2][2];
#pragma unroll
    for (int i2 = 0; i2 < 2; ++i2)
#pragma unroll
        for (int j = 0; j < 2; ++j)
#pragma unroll
            for (int r = 0; r < 16; ++r) acc[i2][j][r] = 0.f;

#pragma unroll
    for (int t = 0; t < 64; ++t) {
        const int s = t % 3;
        const int k0 = t * 16;
        bf16x8 a0 = *(const bf16x8*)(h1s + (0 * 32 + m32) * HP1 + k0 + h8);
        bf16x8 a1 = *(const bf16x8*)(h1s + (1 * 32 + m32) * HP1 + k0 + h8);
        __builtin_amdgcn_s_setprio(1);
        acc[0][0] = __builtin_amdgcn_mfma_f32_32x32x16_bf16(a0, bp[s][0], acc[0][0], 0, 0, 0);
        acc[1][0] = __builtin_amdgcn_mfma_f32_32x32x16_bf16(a1, bp[s][0], acc[1][0], 0, 0, 0);
        acc[0][1] = __builtin_amdgcn_mfma_f32_32x32x16_bf16(a0, bp[s][1], acc[0][1], 0, 0, 0);
        acc[1][1] = __builtin_amdgcn_mfma_f32_32x32x16_bf16(a1, bp[s][1], acc[1][1], 0, 0, 0);
        __builtin_amdgcn_s_setprio(0);
        if (t + 3 < 64) {
            bp[s][0] = *(const bf16x8*)(wq + ((t + 3) * 2 + 0) * 512);
            bp[s][1] = *(const bf16x8*)(wq + ((t + 3) * 2 + 1) * 512);
        }
    }

    // ---- epilogue + Phase C: per 16x32 chunk -> scratch (A-layout) -> logits MFMA
    const float bias2[2] = { bm2[nb0 + m32], bm2[nb0 + 32 + m32] };
    bf16x8 b3f[2];
    b3f[0] = *(const bf16x8*)(W3T + l16 * 1024 + nb0 + 0 * 32 + q * 8);
    b3f[1] = *(const bf16x8*)(W3T + l16 * 1024 + nb0 + 1 * 32 + q * 8);
    f32x4 plog[4];
#pragma unroll
    for (int mt = 0; mt < 4; ++mt) plog[mt] = (f32x4){0.f, 0.f, 0.f, 0.f};
    u16* sw = scr + w * 16 * SCP2;

#pragma unroll
    for (int i2 = 0; i2 < 2; ++i2)
#pragma unroll
        for (int rh = 0; rh < 2; ++rh) {
            const int mt = i2 * 2 + rh;
#pragma unroll
            for (int j = 0; j < 2; ++j) {
#pragma unroll
                for (int rr = 0; rr < 8; ++rr) {
                    // 32x32 C-layout: row=(reg&3)+8*(reg>>2)+4*(lane>>5), col=lane&31
                    const int row16 = (rr & 3) + 8 * (rr >> 2) + 4 * (lane >> 5);
                    float v = acc[i2][j][rh * 8 + rr] + bias2[j];
                    sw[row16 * SCP2 + m32] = f2bf(fmaxf(v, 0.f));
                }
                bf16x8 a2 = *(const bf16x8*)(sw + l16 * SCP2 + q * 8);
                plog[mt] = __builtin_amdgcn_mfma_f32_16x16x32_bf16(a2, b3f[j], plog[mt], 0, 0, 0);
            }
        }

    // ---- cross-wave logit reduction (reuse h1s as f32 buffer: 16*4*64*16B = 64 KB)
    __syncthreads();
    f32x4* red = (f32x4*)h1s;
#pragma unroll
    for (int mt = 0; mt < 4; ++mt) red[(w * 4 + mt) * 64 + lane] = plog[mt];
    __syncthreads();

    if (w < 4) {                                   // wave w finalizes m-tile w
        f32x4 tot = red[w * 64 + lane];
#pragma unroll
        for (int w2 = 1; w2 < 16; ++w2) tot = tot + red[(w2 * 4 + w) * 64 + lane];
        const float b3v = bm3[l16];
#pragma unroll
        for (int r = 0; r < 4; ++r) {
            float v = tot[r] + b3v;
            float m = v;
            m = fmaxf(m, __shfl_xor(m, 1));
            m = fmaxf(m, __shfl_xor(m, 2));
            m = fmaxf(m, __shfl_xor(m, 4));
            m = fmaxf(m, __shfl_xor(m, 8));
            float e = __expf(v - m);
            float s = e;
            s += __shfl_xor(s, 1);
            s += __shfl_xor(s, 2);
            s += __shfl_xor(s, 4);
            s += __shfl_xor(s, 8);
            const int R = row0 + w * 16 + q * 4 + r;
            if (R < N_NODES) {
                logitsO[R * 16 + l16] = v;
                probs[R * 16 + l16] = e / s;
            }
        }
    }
}

extern "C" void kernel_launch(void* const* d_in, const int* in_sizes, int n_in,
                              void* d_out, int out_size, void* d_ws, size_t ws_size,
                              hipStream_t stream) {
    const float* x   = (const float*)d_in[0];
    const int*   ei  = (const int*)d_in[1];
    const int*   src = ei;
    const int*   dst = ei + N_EDGES;
    const float* W1l = (const float*)d_in[2];
    const float* b1l = (const float*)d_in[3];
    const float* W1r = (const float*)d_in[4];
    const float* g1  = (const float*)d_in[5];
    const float* be1 = (const float*)d_in[6];
    const float* W2l = (const float*)d_in[7];
    const float* b2l = (const float*)d_in[8];
    const float* W2r = (const float*)d_in[9];
    const float* g2  = (const float*)d_in[10];
    const float* be2 = (const float*)d_in[11];
    const float* Wm1 = (const float*)d_in[12];
    const float* bm1 = (const float*)d_in[13];
    const float* Wm2 = (const float*)d_in[14];
    const float* bm2 = (const float*)d_in[15];
    const float* Wm3 = (const float*)d_in[16];
    const float* bm3 = (const float*)d_in[17];

    float* probs  = (float*)d_out;                 // [N,16]
    float* logits = probs + 1600000;               // [N,16]
    float* xt1    = probs + 3200000;               // [N,64]
    float* xt2    = probs + 9600000;               // [N,32]

    char* wsb    = (char*)d_ws;
    int*  deg    = (int*)(wsb);                    //   400,000 B
    float* stats = (float*)(wsb + 400000);         //       768 B
    int*  offs   = (int*)(wsb + 400768);           //   400,000 B
    int*  eidx   = (int*)(wsb + 800768);           // 6,400,000 B (ends 7,200,768)
    u16*  xb1    = (u16*)(wsb + 7200768);          // 12,800,000 B bf16 x   (ends 20,000,768)
    u16*  xt1b   = (u16*)(wsb + 20000768);         // 12,800,000 B bf16 xt1 (ends 32,800,768)
    u16*  xt2b   = (u16*)(wsb + 32800768);         // 6,402,048 B ([100032][32])
    u16*  W1T    = (u16*)(wsb + 39202816);         //    65,536 B
    u16*  W2P    = (u16*)(wsb + 39268352);         // 2,097,152 B (fragment-packed Wm2)
    u16*  W3T    = (u16*)(wsb + 41365504);         //    32,768 B  (ends 41,398,272)
    int*  bsum   = (int*)(wsb + 41398272);         //       400 B scan block totals
    float* sum1 = stats, *sq1 = stats + 64, *sum2 = stats + 128, *sq2 = stats + 160;

    // zero deg + stats; zero xt2b tail rows 100000..100031
    hipMemsetAsync(wsb, 0, 400768, stream);
    hipMemsetAsync(xt2b + 100000 * 32, 0, 32 * 32 * sizeof(u16), stream);

    // weight transforms (bf16) + bf16 copy of x (6.4M elems = 3125 blocks x 256 thr x 8)
    cvt_bf16<<<3125, 256, 0, stream>>>(x, xb1);
    transpose_cvt<<<dim3(32, 1),  dim3(32, 8), 0, stream>>>(Wm1, W1T, 32, 1024);
    pack_w2<<<512, 256, 0, stream>>>(Wm2, W2P);
    transpose_cvt<<<dim3(1, 32),  dim3(32, 8), 0, stream>>>(Wm3, W3T, 1024, 16);

    // ---- CSR build (once; reused by both layers)
    hist_deg<<<6250, 256, 0, stream>>>(dst, deg, N_EDGES);
    scan_blk<<<98, 1024, 0, stream>>>(deg, offs, bsum, N_NODES);
    scan_top<<<1, 64, 0, stream>>>(bsum, 98);
    scan_add<<<98, 1024, 0, stream>>>(offs, bsum, N_NODES);
    fill_csr<<<6250, 256, 0, stream>>>(src, dst, offs, eidx, N_EDGES);

    // ---- layer 1: fused gather-mean (bf16 rows, 8 nodes/wave) + SAGE gemm
    agg_sage<64><<<1024, 256, 0, stream>>>((const u16x8*)xb1, (const f32x4*)x,
                                           offs, deg, eidx,
                                           W1l, W1r, b1l, xt1, sum1, sq1, N_NODES);
    bn_relu<64, 1><<<4096, 256, 0, stream>>>(xt1, sum1, sq1, g1, be1, xt1b, N_NODES);

    // ---- layer 2: fused gather-mean (bf16 rows, 8 nodes/wave) + SAGE gemm
    agg_sage<32><<<1024, 256, 0, stream>>>((const u16x8*)xt1b, (const f32x4*)xt1,
                                           offs, deg, eidx,
                                           W2l, W2r, b2l, xt2, sum2, sq2, N_NODES);
    bn_relu<32, 1><<<2048, 256, 0, stream>>>(xt2, sum2, sq2, g2, be2, xt2b, N_NODES);

    // ---- fused MLP + softmax
    mlp_fused<<<1563, 1024, 0, stream>>>(xt2b, W1T, bm1, W2P, bm2, W3T, bm3, probs, logits);
}